// Round 12
// baseline (443.703 us; speedup 1.0000x reference)
//
#include <hip/hip_runtime.h>
#include <hip/hip_bf16.h>
#include <math.h>

#define D 512
#define BB 4
#define TT 4096
#define KT 32

typedef __attribute__((ext_vector_type(8))) short short8v;
typedef __attribute__((ext_vector_type(4))) short short4v;
typedef __attribute__((ext_vector_type(4))) float float4v;

__device__ inline short f2bf(float x) {
    __hip_bfloat16 h = __float2bfloat16(x);
    return *reinterpret_cast<short*>(&h);
}

// ============ QKV projection: C[t][e] = alpha * sum_d x[t][d] * W[e][d], bf16 out ============
__global__ __launch_bounds__(256) void gemm_qkv(
    const float* __restrict__ x,
    const float* __restrict__ Wq, const float* __restrict__ Wk, const float* __restrict__ Wv,
    __hip_bfloat16* __restrict__ q, __hip_bfloat16* __restrict__ k, __hip_bfloat16* __restrict__ v)
{
    const float* W; __hip_bfloat16* C; float alpha;
    if (blockIdx.z == 0)      { W = Wq; C = q; alpha = 0.044194173824159216f; } // fold 1/sqrt(512)
    else if (blockIdx.z == 1) { W = Wk; C = k; alpha = 1.f; }
    else                      { W = Wv; C = v; alpha = 1.f; }

    __shared__ short As[64][72];   // +8 bf16 pad -> conflict-floor b128 reads
    __shared__ short Bs[64][72];
    const int tid = threadIdx.x;
    const int m0 = blockIdx.x * 64, n0 = blockIdx.y * 64;
    const int w = tid >> 6, lane = tid & 63, lm = lane & 15, g = lane >> 4;

    float4v acc[4];
    #pragma unroll
    for (int i = 0; i < 4; ++i) acc[i] = (float4v){0.f,0.f,0.f,0.f};

    for (int k0 = 0; k0 < 512; k0 += 64) {
        __syncthreads();
        #pragma unroll
        for (int u = 0; u < 4; ++u) {          // stage A (x), convert f32->bf16
            int ch = tid + 256*u;
            int r = ch >> 4, c = (ch & 15) * 4;
            float4 xv = *reinterpret_cast<const float4*>(x + (size_t)(m0 + r)*512 + k0 + c);
            short4v sv = { f2bf(xv.x), f2bf(xv.y), f2bf(xv.z), f2bf(xv.w) };
            *reinterpret_cast<short4v*>(&As[r][c]) = sv;
        }
        #pragma unroll
        for (int u = 0; u < 4; ++u) {          // stage B (W rows)
            int ch = tid + 256*u;
            int r = ch >> 4, c = (ch & 15) * 4;
            float4 wv = *reinterpret_cast<const float4*>(W + (size_t)(n0 + r)*512 + k0 + c);
            short4v sv = { f2bf(wv.x), f2bf(wv.y), f2bf(wv.z), f2bf(wv.w) };
            *reinterpret_cast<short4v*>(&Bs[r][c]) = sv;
        }
        __syncthreads();
        #pragma unroll
        for (int ks = 0; ks < 2; ++ks) {
            short8v a = *reinterpret_cast<const short8v*>(&As[16*w + lm][ks*32 + 8*g]);
            #pragma unroll
            for (int nt = 0; nt < 4; ++nt) {
                short8v bv = *reinterpret_cast<const short8v*>(&Bs[16*nt + lm][ks*32 + 8*g]);
                acc[nt] = __builtin_amdgcn_mfma_f32_16x16x32_bf16(a, bv, acc[nt], 0, 0, 0);
            }
        }
    }
    #pragma unroll
    for (int nt = 0; nt < 4; ++nt)
        #pragma unroll
        for (int r = 0; r < 4; ++r) {
            int row = m0 + 16*w + 4*g + r;     // D: row = 4*(lane>>4)+reg, col = lane&15
            int col = n0 + 16*nt + lm;
            C[(size_t)row*512 + col] = __float2bfloat16(acc[nt][r] * alpha);
        }
}

// ============ V transpose with sigma-permuted columns ============
// vt[b][d][32-block of t, order pos(tau)]: pos(tau) = 8*((tau&15)>>2) + (tau&3) + 4*(tau>>4)
// -> position 8g+e within a 32-key block holds key sigma(g,e) = {4g+e, 16+4g+(e-4)}.
__global__ __launch_bounds__(256) void transpose_v(
    const __hip_bfloat16* __restrict__ vin, __hip_bfloat16* __restrict__ vout)
{
    const int tid = threadIdx.x;
    const int b = blockIdx.y;
    const int t = blockIdx.x * 32 + (tid & 31);
    const int tau = t & 31;
    const int tp = (t & ~31) + 8*((tau & 15) >> 2) + (tau & 3) + 4*(tau >> 4);
    const short* src = (const short*)vin + (size_t)(b*TT + t)*D;
    short* dst = (short*)vout + (size_t)b*D*TT;
    #pragma unroll
    for (int u = 0; u < 8; ++u) {
        int cf = (tid >> 5) + 8*u;             // 0..63 (16B chunk within row)
        short8v vv = *reinterpret_cast<const short8v*>(src + cf*8);
        #pragma unroll
        for (int i = 0; i < 8; ++i)
            dst[(size_t)(cf*8 + i)*TT + tp] = vv[i];
    }
}

// ============ Flash attention: triangle-paired, software-pipelined ============
// Iteration t computes QK(t+1) [independent] interleaved with SM(t)+PV(t) [dependent],
// collapsing the serial QK->SM->PV chain to ~max(QK, SM+PV). Buffering: K double (QK(t+1)
// pre-read needs stage 2 ahead), V TRIPLE (stage(t+2) must not touch PV(t)'s buffer).
// LDS = 64KB K + 96KB V = 160KB. Stage order per iteration: barrier -> STAGE(t+2) ->
// QK(t+1) -> SM(t) -> PV(t). All cross-wave hazards separated by the per-tile barrier.
__global__ __launch_bounds__(256, 1) void attn(
    const __hip_bfloat16* __restrict__ qg, const __hip_bfloat16* __restrict__ kg,
    const __hip_bfloat16* __restrict__ vtg, __hip_bfloat16* __restrict__ ctx)
{
    __shared__ short Ks[2][KT][512];           // 64KB; row r chunk c holds K chunk c^((r&15)<<2)
    __shared__ short Vs[3][512][32];           // 96KB; row d chunk c holds vt chunk c^((d>>1)&3)

    const int tid = threadIdx.x;
    const int w = tid >> 6, lane = tid & 63, lm = lane & 15, g = lane >> 4;
    const int qgp = w & 1, dh = w >> 1;
    const int idx = blockIdx.x;
    const int b  = idx & 3;                    // batch -> XCD spread
    const int pr = idx >> 2;                   // pair index 0..63

    const short* qp = (const short*)qg  + (size_t)b*TT*D;
    const short* kp = (const short*)kg  + (size_t)b*TT*D;
    const short* vp = (const short*)vtg + (size_t)b*D*TT;
    __hip_bfloat16* cp = ctx + (size_t)b*TT*D;

    const int vswz = (lane & 3) ^ ((lane >> 3) & 3);   // V stage: source chunk for this lane

    // per-lane LDS base pointers (element = short); buffer strides: K 16384, V 16384 shorts
    const short* k0p = &Ks[0][lm][g*8];        // QK read: kc + 32*(s^lm); second subtile +8192
    const short* k1p = &Ks[1][lm][g*8];
    const int vcid = g ^ ((lm >> 1) & 3);
    const short* v0p = &Vs[0][256*dh + lm][vcid*8];    // PV read: vc + dt*512 (literal)

    // stage tile T: K rows -> K-buffer KB, V^T dims -> V-buffer VB (source pre-XOR-swizzled)
    #define STAGE_KV(T, KB, VB) do {                                               \
        const short* kt_ = kp + (size_t)(T) * KT * D;                              \
        const int ksv_ = (T) * KT;                                                 \
        short* kd_ = (short*)Ks + (KB)*16384;                                      \
        short* vd_ = (short*)Vs + (VB)*16384;                                      \
        _Pragma("unroll")                                                          \
        for (int i_ = 0; i_ < 8; ++i_) {                                           \
            int r_ = 8*w + i_;                                                     \
            int c_ = (lane ^ ((r_ & 15) << 2)) & 63;                               \
            __builtin_amdgcn_global_load_lds(                                      \
                (const __attribute__((address_space(1))) void*)(kt_ + (size_t)r_*D + c_*8), \
                (__attribute__((address_space(3))) void*)(kd_ + r_*512),           \
                16, 0, 0);                                                         \
        }                                                                          \
        _Pragma("unroll")                                                          \
        for (int i_ = 0; i_ < 8; ++i_) {                                           \
            int d0_ = 128*w + 16*i_;                                               \
            int row_ = d0_ + (lane >> 2);                                          \
            __builtin_amdgcn_global_load_lds(                                      \
                (const __attribute__((address_space(1))) void*)(vp + (size_t)row_*TT + ksv_ + vswz*8), \
                (__attribute__((address_space(3))) void*)(vd_ + d0_*32),           \
                16, 0, 0);                                                         \
        }                                                                          \
    } while (0)

    // QK for one tile: 4 independent 8-deep MFMA chains, swizzled conflict-free reads
    short8v qf[16];
    auto QK = [&](const short* kc, float4v& so0, float4v& so1) {
        float4v c0a = (float4v){0.f,0.f,0.f,0.f}, c0b = (float4v){0.f,0.f,0.f,0.f};
        float4v c1a = (float4v){0.f,0.f,0.f,0.f}, c1b = (float4v){0.f,0.f,0.f,0.f};
        #pragma unroll
        for (int s = 0; s < 16; ++s) {
            int off = (s ^ lm) << 5;           // shorts: 32*(s^lm)
            short8v a0 = *reinterpret_cast<const short8v*>(kc + off);
            short8v a1 = *reinterpret_cast<const short8v*>(kc + off + 8192);
            if (s & 1) {
                c0b = __builtin_amdgcn_mfma_f32_16x16x32_bf16(a0, qf[s], c0b, 0, 0, 0);
                c1b = __builtin_amdgcn_mfma_f32_16x16x32_bf16(a1, qf[s], c1b, 0, 0, 0);
            } else {
                c0a = __builtin_amdgcn_mfma_f32_16x16x32_bf16(a0, qf[s], c0a, 0, 0, 0);
                c1a = __builtin_amdgcn_mfma_f32_16x16x32_bf16(a1, qf[s], c1a, 0, 0, 0);
            }
        }
        #pragma unroll
        for (int r = 0; r < 4; ++r) { so0[r] = c0a[r] + c0b[r]; so1[r] = c1a[r] + c1b[r]; }
    };

    #pragma unroll 1
    for (int phase = 0; phase < 2; ++phase) {
        const int qb = phase ? (127 - pr) : pr;
        const int qbase = qb * 32;
        const int qrow  = qbase + 16*qgp + lm;
        const int ntiles = qb + 1;

        // hoist Q fragments: lane (g,lm) holds Q[qrow][32s+8g .. +8]
        #pragma unroll
        for (int s = 0; s < 16; ++s)
            qf[s] = *reinterpret_cast<const short8v*>(qp + (size_t)qrow*D + 32*s + 8*g);

        float4v acc[16];                       // O^T: col=q=lm, rows=dims 256*dh+16*dt+4g+r
        #pragma unroll
        for (int i = 0; i < 16; ++i) acc[i] = (float4v){0.f,0.f,0.f,0.f};
        float m_r = -INFINITY, l_par = 0.f;    // l_par: this lane's 8-kj partial sum

        __syncthreads();                       // prev phase's LDS reads done before re-staging
        STAGE_KV(0, 0, 0);
        __syncthreads();                       // stage(0) landed for all waves
        if (ntiles > 1) STAGE_KV(1, 1, 1);

        float4v s0, s1;
        QK(k0p, s0, s1);                       // QK(0) from k-buffer 0

        int vr = 0;                            // V buffer holding tile t
        int vs = 2;                            // V buffer for stage target (t+2)%3
        for (int t = 0; t < ntiles; ++t) {
            const int ks0 = t * KT;
            __syncthreads();                   // stage(t+1) landed; all waves' QK(t) done;
                                               // reads of K(t-1)/V(t-1) complete
            if (t + 2 < ntiles) STAGE_KV(t + 2, t & 1, vs);

            float4v n0, n1;                    // QK(t+1), interleaves with SM(t)+PV(t) below
            if (t + 1 < ntiles) QK(((t + 1) & 1) ? k1p : k0p, n0, n1);

            // SM(t): causal mask + online softmax on s0,s1 (computed last iteration)
            float p[8];
            #pragma unroll
            for (int r = 0; r < 4; ++r) {
                int kj0 = ks0 + 4*g + r;
                p[r]     = (kj0      <= qrow) ? s0[r] : -3.0e38f;
                p[r + 4] = (kj0 + 16 <= qrow) ? s1[r] : -3.0e38f;
            }
            float mx = p[0];
            #pragma unroll
            for (int i = 1; i < 8; ++i) mx = fmaxf(mx, p[i]);

            // defer-max: row-max shuffles + rescale only when slack exceeded (or first tile)
            if (!__all(mx <= m_r + 8.f)) {
                float mrow = fmaxf(mx, __shfl_xor(mx, 16));
                mrow = fmaxf(mrow, __shfl_xor(mrow, 32));
                mrow = fmaxf(mrow, m_r);
                float corr = __expf(m_r - mrow);   // first tile: expf(-inf)=0
                m_r = mrow;
                l_par *= corr;
                #pragma unroll
                for (int dt = 0; dt < 16; ++dt) {
                    acc[dt][0] *= corr; acc[dt][1] *= corr;
                    acc[dt][2] *= corr; acc[dt][3] *= corr;
                }
            }
            #pragma unroll
            for (int i = 0; i < 8; ++i) { p[i] = __expf(p[i] - m_r); l_par += p[i]; }

            // P fragment (lane-local): B-operand elems = P[q=lm][sigma(g,e)], values <= e^8
            short8v pf;
            #pragma unroll
            for (int i = 0; i < 8; ++i) pf[i] = f2bf(p[i]);

            // PV(t) (O^T): A = V^T rows from LDS at literal offsets, B = pf
            const short* vc = v0p + (vr << 14);    // buffer stride 16384 shorts
            #pragma unroll
            for (int dt = 0; dt < 16; ++dt) {
                short8v vf = *reinterpret_cast<const short8v*>(vc + dt*512);
                acc[dt] = __builtin_amdgcn_mfma_f32_16x16x32_bf16(vf, pf, acc[dt], 0, 0, 0);
            }

            s0 = n0; s1 = n1;                  // rotate pipeline state
            vr = (vr == 2) ? 0 : vr + 1;
            vs = (vs == 2) ? 0 : vs + 1;
        }

        // phase epilogue: reduce l across the row's 4 g-lanes, lane-local normalize, store
        float l = l_par + __shfl_xor(l_par, 16);
        l += __shfl_xor(l, 32);
        float inv = 1.f / l;
        const int orow = qbase + 16*qgp + lm;
        #pragma unroll
        for (int dt = 0; dt < 16; ++dt) {
            short4v o = { f2bf(acc[dt][0]*inv), f2bf(acc[dt][1]*inv),
                          f2bf(acc[dt][2]*inv), f2bf(acc[dt][3]*inv) };
            *reinterpret_cast<short4v*>((short*)cp + (size_t)orow*D + 256*dh + 16*dt + 4*g) = o;
        }
    }
    #undef STAGE_KV
}

// ============ Output projection: d_out[t][e] = sum_d ctx[t][d] * Wo[e][d], f32 out ============
__global__ __launch_bounds__(256) void gemm_out(
    const __hip_bfloat16* __restrict__ Ab, const float* __restrict__ W,
    float* __restrict__ Cf)
{
    __shared__ short As[64][72];
    __shared__ short Bs[64][72];
    const int tid = threadIdx.x;
    const int m0 = blockIdx.x * 64, n0 = blockIdx.y * 64;
    const int w = tid >> 6, lane = tid & 63, lm = lane & 15, g = lane >> 4;
    const short* Ap = (const short*)Ab;

    float4v acc[4];
    #pragma unroll
    for (int i = 0; i < 4; ++i) acc[i] = (float4v){0.f,0.f,0.f,0.f};

    for (int k0 = 0; k0 < 512; k0 += 64) {
        __syncthreads();
        #pragma unroll
        for (int u = 0; u < 2; ++u) {          // stage A (bf16 ctx)
            int ch = tid + 256*u;
            int r = ch >> 3, c = (ch & 7) * 8;
            *reinterpret_cast<short8v*>(&As[r][c]) =
                *reinterpret_cast<const short8v*>(Ap + (size_t)(m0 + r)*512 + k0 + c);
        }
        #pragma unroll
        for (int u = 0; u < 4; ++u) {          // stage B (Wo f32 -> bf16)
            int ch = tid + 256*u;
            int r = ch >> 4, c = (ch & 15) * 4;
            float4 wv = *reinterpret_cast<const float4*>(W + (size_t)(n0 + r)*512 + k0 + c);
            short4v sv = { f2bf(wv.x), f2bf(wv.y), f2bf(wv.z), f2bf(wv.w) };
            *reinterpret_cast<short4v*>(&Bs[r][c]) = sv;
        }
        __syncthreads();
        #pragma unroll
        for (int ks = 0; ks < 2; ++ks) {
            short8v a = *reinterpret_cast<const short8v*>(&As[16*w + lm][ks*32 + 8*g]);
            #pragma unroll
            for (int nt = 0; nt < 4; ++nt) {
                short8v bv = *reinterpret_cast<const short8v*>(&Bs[16*nt + lm][ks*32 + 8*g]);
                acc[nt] = __builtin_amdgcn_mfma_f32_16x16x32_bf16(a, bv, acc[nt], 0, 0, 0);
            }
        }
    }
    #pragma unroll
    for (int nt = 0; nt < 4; ++nt)
        #pragma unroll
        for (int r = 0; r < 4; ++r) {
            int row = m0 + 16*w + 4*g + r;
            int col = n0 + 16*nt + lm;
            Cf[(size_t)row*512 + col] = acc[nt][r];
        }
}

extern "C" void kernel_launch(void* const* d_in, const int* in_sizes, int n_in,
                              void* d_out, int out_size, void* d_ws, size_t ws_size,
                              hipStream_t stream) {
    const float* x  = (const float*)d_in[0];
    const float* Wq = (const float*)d_in[1];
    const float* Wk = (const float*)d_in[2];
    const float* Wv = (const float*)d_in[3];
    const float* Wo = (const float*)d_in[4];
    float* out = (float*)d_out;

    const size_t n = (size_t)BB * TT * D;                 // 8.4M elems
    __hip_bfloat16* qb   = (__hip_bfloat16*)d_ws;
    __hip_bfloat16* kb   = qb + n;
    __hip_bfloat16* vb   = kb + n;
    __hip_bfloat16* vt   = vb + n;
    __hip_bfloat16* ctxb = vt + n;                        // total 5n*2B = 80MB

    gemm_qkv<<<dim3(256, 8, 3), 256, 0, stream>>>(x, Wq, Wk, Wv, qb, kb, vb);
    transpose_v<<<dim3(TT / 32, BB), 256, 0, stream>>>(vb, vt);
    attn<<<dim3(64 * BB), 256, 0, stream>>>(qb, kb, vt, ctxb);
    gemm_out<<<dim3(256, 8, 1), 256, 0, stream>>>(ctxb, Wo, out);
}

// Round 13
// 409.740 us; speedup vs baseline: 1.0829x; 1.0829x over previous
//
#include <hip/hip_runtime.h>
#include <hip/hip_bf16.h>
#include <math.h>

#define D 512
#define BB 4
#define TT 4096
#define KT 32

typedef __attribute__((ext_vector_type(8))) short short8v;
typedef __attribute__((ext_vector_type(4))) short short4v;
typedef __attribute__((ext_vector_type(4))) float float4v;

__device__ inline short f2bf(float x) {
    __hip_bfloat16 h = __float2bfloat16(x);
    return *reinterpret_cast<short*>(&h);
}

// ============ QKV projection: C[t][e] = alpha * sum_d x[t][d] * W[e][d], bf16 out ============
__global__ __launch_bounds__(256) void gemm_qkv(
    const float* __restrict__ x,
    const float* __restrict__ Wq, const float* __restrict__ Wk, const float* __restrict__ Wv,
    __hip_bfloat16* __restrict__ q, __hip_bfloat16* __restrict__ k, __hip_bfloat16* __restrict__ v)
{
    const float* W; __hip_bfloat16* C; float alpha;
    if (blockIdx.z == 0)      { W = Wq; C = q; alpha = 0.044194173824159216f; } // fold 1/sqrt(512)
    else if (blockIdx.z == 1) { W = Wk; C = k; alpha = 1.f; }
    else                      { W = Wv; C = v; alpha = 1.f; }

    __shared__ short As[64][72];   // +8 bf16 pad -> conflict-floor b128 reads
    __shared__ short Bs[64][72];
    const int tid = threadIdx.x;
    const int m0 = blockIdx.x * 64, n0 = blockIdx.y * 64;
    const int w = tid >> 6, lane = tid & 63, lm = lane & 15, g = lane >> 4;

    float4v acc[4];
    #pragma unroll
    for (int i = 0; i < 4; ++i) acc[i] = (float4v){0.f,0.f,0.f,0.f};

    for (int k0 = 0; k0 < 512; k0 += 64) {
        __syncthreads();
        #pragma unroll
        for (int u = 0; u < 4; ++u) {          // stage A (x), convert f32->bf16
            int ch = tid + 256*u;
            int r = ch >> 4, c = (ch & 15) * 4;
            float4 xv = *reinterpret_cast<const float4*>(x + (size_t)(m0 + r)*512 + k0 + c);
            short4v sv = { f2bf(xv.x), f2bf(xv.y), f2bf(xv.z), f2bf(xv.w) };
            *reinterpret_cast<short4v*>(&As[r][c]) = sv;
        }
        #pragma unroll
        for (int u = 0; u < 4; ++u) {          // stage B (W rows)
            int ch = tid + 256*u;
            int r = ch >> 4, c = (ch & 15) * 4;
            float4 wv = *reinterpret_cast<const float4*>(W + (size_t)(n0 + r)*512 + k0 + c);
            short4v sv = { f2bf(wv.x), f2bf(wv.y), f2bf(wv.z), f2bf(wv.w) };
            *reinterpret_cast<short4v*>(&Bs[r][c]) = sv;
        }
        __syncthreads();
        #pragma unroll
        for (int ks = 0; ks < 2; ++ks) {
            short8v a = *reinterpret_cast<const short8v*>(&As[16*w + lm][ks*32 + 8*g]);
            #pragma unroll
            for (int nt = 0; nt < 4; ++nt) {
                short8v bv = *reinterpret_cast<const short8v*>(&Bs[16*nt + lm][ks*32 + 8*g]);
                acc[nt] = __builtin_amdgcn_mfma_f32_16x16x32_bf16(a, bv, acc[nt], 0, 0, 0);
            }
        }
    }
    #pragma unroll
    for (int nt = 0; nt < 4; ++nt)
        #pragma unroll
        for (int r = 0; r < 4; ++r) {
            int row = m0 + 16*w + 4*g + r;     // D: row = 4*(lane>>4)+reg, col = lane&15
            int col = n0 + 16*nt + lm;
            C[(size_t)row*512 + col] = __float2bfloat16(acc[nt][r] * alpha);
        }
}

// ============ V transpose with sigma-permuted columns ============
// vt[b][d][32-block of t, order pos(tau)]: pos(tau) = 8*((tau&15)>>2) + (tau&3) + 4*(tau>>4)
// -> position 8g+e within a 32-key block holds key sigma(g,e) = {4g+e, 16+4g+(e-4)}.
__global__ __launch_bounds__(256) void transpose_v(
    const __hip_bfloat16* __restrict__ vin, __hip_bfloat16* __restrict__ vout)
{
    const int tid = threadIdx.x;
    const int b = blockIdx.y;
    const int t = blockIdx.x * 32 + (tid & 31);
    const int tau = t & 31;
    const int tp = (t & ~31) + 8*((tau & 15) >> 2) + (tau & 3) + 4*(tau >> 4);
    const short* src = (const short*)vin + (size_t)(b*TT + t)*D;
    short* dst = (short*)vout + (size_t)b*D*TT;
    #pragma unroll
    for (int u = 0; u < 8; ++u) {
        int cf = (tid >> 5) + 8*u;             // 0..63 (16B chunk within row)
        short8v vv = *reinterpret_cast<const short8v*>(src + cf*8);
        #pragma unroll
        for (int i = 0; i < 8; ++i)
            dst[(size_t)(cf*8 + i)*TT + tp] = vv[i];
    }
}

// ============ Flash attention: 8 waves = 2 q-groups x 4 d-quarters, triangle-paired ============
// TLP is bought INSIDE the block: 8 waves -> 2 waves/SIMD guaranteed co-resident, so each
// SIMD interleaves two waves' instructions and hides ds_read/MFMA/softmax latencies. QK is
// computed redundantly x4 (per d-quarter) -- spending the idle MFMA pipe to buy latency
// hiding. Wave (qgp,dq): 16 q-rows x 128 output dims; acc = 8 float4v. Structure otherwise
// R11-verbatim: K+V double-buffered 128KB LDS, source-XOR swizzles, pointer-toggle
// addressing, O^T PV, defer-max (THR=8), per-lane partial l, triangle pairing (129 tiles).
__global__ __launch_bounds__(512, 1) void attn(
    const __hip_bfloat16* __restrict__ qg, const __hip_bfloat16* __restrict__ kg,
    const __hip_bfloat16* __restrict__ vtg, __hip_bfloat16* __restrict__ ctx)
{
    __shared__ short Ks[2][KT][512];           // 64KB; row r chunk c holds K chunk c^((r&15)<<2)
    __shared__ short Vs[2][512][32];           // 64KB; row d chunk c holds vt chunk c^((d>>1)&3)

    const int tid = threadIdx.x;
    const int w = tid >> 6, lane = tid & 63, lm = lane & 15, g = lane >> 4;
    const int qgp = w & 1, dq = w >> 1;        // q-group 0..1, d-quarter 0..3
    const int idx = blockIdx.x;
    const int b  = idx & 3;                    // batch -> XCD spread
    const int pr = idx >> 2;                   // pair index 0..63

    const short* qp = (const short*)qg  + (size_t)b*TT*D;
    const short* kp = (const short*)kg  + (size_t)b*TT*D;
    const short* vp = (const short*)vtg + (size_t)b*D*TT;
    __hip_bfloat16* cp = ctx + (size_t)b*TT*D;

    const int vswz = (lane & 3) ^ ((lane >> 3) & 3);   // V stage: source chunk for this lane

    // per-lane LDS base pointers (element = short)
    const short* k0p = &Ks[0][lm][g*8];        // QK read: kc + 32*(s^lm); second subtile +8192
    const short* k1p = &Ks[1][lm][g*8];
    const int vcid = g ^ ((lm >> 1) & 3);
    const short* v0p = &Vs[0][128*dq + lm][vcid*8];    // PV read: vc + dt*512 (literal)
    const short* v1p = &Vs[1][128*dq + lm][vcid*8];

    // stage tile T (K rows + V^T dims) into buffer BUF; 8 waves split the 64 DMA instrs
    #define STAGE_KV(T, BUF) do {                                                  \
        const short* kt_ = kp + (size_t)(T) * KT * D;                              \
        const int ksv_ = (T) * KT;                                                 \
        _Pragma("unroll")                                                          \
        for (int i_ = 0; i_ < 4; ++i_) {                                           \
            int r_ = 4*w + i_;                                                     \
            int c_ = (lane ^ ((r_ & 15) << 2)) & 63;                               \
            __builtin_amdgcn_global_load_lds(                                      \
                (const __attribute__((address_space(1))) void*)(kt_ + (size_t)r_*D + c_*8), \
                (__attribute__((address_space(3))) void*)(&Ks[BUF][r_][0]),        \
                16, 0, 0);                                                         \
        }                                                                          \
        _Pragma("unroll")                                                          \
        for (int i_ = 0; i_ < 4; ++i_) {                                           \
            int d0_ = 64*w + 16*i_;                                                \
            int row_ = d0_ + (lane >> 2);                                          \
            __builtin_amdgcn_global_load_lds(                                      \
                (const __attribute__((address_space(1))) void*)(vp + (size_t)row_*TT + ksv_ + vswz*8), \
                (__attribute__((address_space(3))) void*)(&Vs[BUF][d0_][0]),       \
                16, 0, 0);                                                         \
        }                                                                          \
    } while (0)

    #pragma unroll 1
    for (int phase = 0; phase < 2; ++phase) {
        const int qb = phase ? (127 - pr) : pr;
        const int qbase = qb * 32;
        const int qrow  = qbase + 16*qgp + lm;
        const int ntiles = qb + 1;

        // hoist Q fragments for this phase: lane (g,lm) holds Q[qrow][32s+8g .. +8]
        short8v qf[16];
        #pragma unroll
        for (int s = 0; s < 16; ++s)
            qf[s] = *reinterpret_cast<const short8v*>(qp + (size_t)qrow*D + 32*s + 8*g);

        float4v acc[8];                        // O^T: col=q=lm, rows=dims 128*dq+16*dt+4g+r
        #pragma unroll
        for (int i = 0; i < 8; ++i) acc[i] = (float4v){0.f,0.f,0.f,0.f};
        float m_r = -INFINITY, l_par = 0.f;    // l_par: this lane's 8-kj partial sum

        __syncthreads();                       // prev phase's LDS reads done before re-staging
        STAGE_KV(0, 0);

        for (int t = 0; t < ntiles; ++t) {
            const int ks0 = t * KT;
            __syncthreads();                   // own vmcnt drained pre-barrier -> stage(t)
                                               // landed for all waves; reads of t-1 done
            if (t + 1 < ntiles) STAGE_KV(t + 1, (t + 1) & 1);

            const short* kc = (t & 1) ? k1p : k0p;
            const short* vc = (t & 1) ? v1p : v0p;

            // S^T[kj][q]: 4 independent 8-deep MFMA chains
            float4v s0a = (float4v){0.f,0.f,0.f,0.f}, s0b = (float4v){0.f,0.f,0.f,0.f};
            float4v s1a = (float4v){0.f,0.f,0.f,0.f}, s1b = (float4v){0.f,0.f,0.f,0.f};
            #pragma unroll
            for (int s = 0; s < 16; ++s) {
                int off = (s ^ lm) << 5;       // shorts: 32*(s^lm)
                short8v a0 = *reinterpret_cast<const short8v*>(kc + off);
                short8v a1 = *reinterpret_cast<const short8v*>(kc + off + 8192);
                if (s & 1) {
                    s0b = __builtin_amdgcn_mfma_f32_16x16x32_bf16(a0, qf[s], s0b, 0, 0, 0);
                    s1b = __builtin_amdgcn_mfma_f32_16x16x32_bf16(a1, qf[s], s1b, 0, 0, 0);
                } else {
                    s0a = __builtin_amdgcn_mfma_f32_16x16x32_bf16(a0, qf[s], s0a, 0, 0, 0);
                    s1a = __builtin_amdgcn_mfma_f32_16x16x32_bf16(a1, qf[s], s1a, 0, 0, 0);
                }
            }
            float4v s0, s1;
            #pragma unroll
            for (int r = 0; r < 4; ++r) { s0[r] = s0a[r] + s0b[r]; s1[r] = s1a[r] + s1b[r]; }

            // causal mask; lane holds kj = ks0 + sigma(g,e) for q = qrow
            float p[8];
            #pragma unroll
            for (int r = 0; r < 4; ++r) {
                int kj0 = ks0 + 4*g + r;
                p[r]     = (kj0      <= qrow) ? s0[r] : -3.0e38f;
                p[r + 4] = (kj0 + 16 <= qrow) ? s1[r] : -3.0e38f;
            }
            float mx = p[0];
            #pragma unroll
            for (int i = 1; i < 8; ++i) mx = fmaxf(mx, p[i]);

            // defer-max: row-max shuffles + rescale only when slack exceeded (or first tile)
            if (!__all(mx <= m_r + 8.f)) {
                float mrow = fmaxf(mx, __shfl_xor(mx, 16));
                mrow = fmaxf(mrow, __shfl_xor(mrow, 32));
                mrow = fmaxf(mrow, m_r);
                float corr = __expf(m_r - mrow);   // first tile: expf(-inf)=0
                m_r = mrow;
                l_par *= corr;
                #pragma unroll
                for (int dt = 0; dt < 8; ++dt) {
                    acc[dt][0] *= corr; acc[dt][1] *= corr;
                    acc[dt][2] *= corr; acc[dt][3] *= corr;
                }
            }
            #pragma unroll
            for (int i = 0; i < 8; ++i) { p[i] = __expf(p[i] - m_r); l_par += p[i]; }

            // P fragment (lane-local): B-operand elems = P[q=lm][sigma(g,e)], values <= e^8
            short8v pf;
            #pragma unroll
            for (int i = 0; i < 8; ++i) pf[i] = f2bf(p[i]);

            // PV(t) (O^T): A = V^T rows of this wave's d-quarter, literal offsets, B = pf
            #pragma unroll
            for (int dt = 0; dt < 8; ++dt) {
                short8v vf = *reinterpret_cast<const short8v*>(vc + dt*512);
                acc[dt] = __builtin_amdgcn_mfma_f32_16x16x32_bf16(vf, pf, acc[dt], 0, 0, 0);
            }
        }

        // phase epilogue: reduce l across the row's 4 g-lanes, lane-local normalize, store
        float l = l_par + __shfl_xor(l_par, 16);
        l += __shfl_xor(l, 32);
        float inv = 1.f / l;
        const int orow = qbase + 16*qgp + lm;
        #pragma unroll
        for (int dt = 0; dt < 8; ++dt) {
            short4v o = { f2bf(acc[dt][0]*inv), f2bf(acc[dt][1]*inv),
                          f2bf(acc[dt][2]*inv), f2bf(acc[dt][3]*inv) };
            *reinterpret_cast<short4v*>((short*)cp + (size_t)orow*D + 128*dq + 16*dt + 4*g) = o;
        }
    }
    #undef STAGE_KV
}

// ============ Output projection: d_out[t][e] = sum_d ctx[t][d] * Wo[e][d], f32 out ============
__global__ __launch_bounds__(256) void gemm_out(
    const __hip_bfloat16* __restrict__ Ab, const float* __restrict__ W,
    float* __restrict__ Cf)
{
    __shared__ short As[64][72];
    __shared__ short Bs[64][72];
    const int tid = threadIdx.x;
    const int m0 = blockIdx.x * 64, n0 = blockIdx.y * 64;
    const int w = tid >> 6, lane = tid & 63, lm = lane & 15, g = lane >> 4;
    const short* Ap = (const short*)Ab;

    float4v acc[4];
    #pragma unroll
    for (int i = 0; i < 4; ++i) acc[i] = (float4v){0.f,0.f,0.f,0.f};

    for (int k0 = 0; k0 < 512; k0 += 64) {
        __syncthreads();
        #pragma unroll
        for (int u = 0; u < 2; ++u) {          // stage A (bf16 ctx)
            int ch = tid + 256*u;
            int r = ch >> 3, c = (ch & 7) * 8;
            *reinterpret_cast<short8v*>(&As[r][c]) =
                *reinterpret_cast<const short8v*>(Ap + (size_t)(m0 + r)*512 + k0 + c);
        }
        #pragma unroll
        for (int u = 0; u < 4; ++u) {          // stage B (Wo f32 -> bf16)
            int ch = tid + 256*u;
            int r = ch >> 4, c = (ch & 15) * 4;
            float4 wv = *reinterpret_cast<const float4*>(W + (size_t)(n0 + r)*512 + k0 + c);
            short4v sv = { f2bf(wv.x), f2bf(wv.y), f2bf(wv.z), f2bf(wv.w) };
            *reinterpret_cast<short4v*>(&Bs[r][c]) = sv;
        }
        __syncthreads();
        #pragma unroll
        for (int ks = 0; ks < 2; ++ks) {
            short8v a = *reinterpret_cast<const short8v*>(&As[16*w + lm][ks*32 + 8*g]);
            #pragma unroll
            for (int nt = 0; nt < 4; ++nt) {
                short8v bv = *reinterpret_cast<const short8v*>(&Bs[16*nt + lm][ks*32 + 8*g]);
                acc[nt] = __builtin_amdgcn_mfma_f32_16x16x32_bf16(a, bv, acc[nt], 0, 0, 0);
            }
        }
    }
    #pragma unroll
    for (int nt = 0; nt < 4; ++nt)
        #pragma unroll
        for (int r = 0; r < 4; ++r) {
            int row = m0 + 16*w + 4*g + r;
            int col = n0 + 16*nt + lm;
            Cf[(size_t)row*512 + col] = acc[nt][r];
        }
}

extern "C" void kernel_launch(void* const* d_in, const int* in_sizes, int n_in,
                              void* d_out, int out_size, void* d_ws, size_t ws_size,
                              hipStream_t stream) {
    const float* x  = (const float*)d_in[0];
    const float* Wq = (const float*)d_in[1];
    const float* Wk = (const float*)d_in[2];
    const float* Wv = (const float*)d_in[3];
    const float* Wo = (const float*)d_in[4];
    float* out = (float*)d_out;

    const size_t n = (size_t)BB * TT * D;                 // 8.4M elems
    __hip_bfloat16* qb   = (__hip_bfloat16*)d_ws;
    __hip_bfloat16* kb   = qb + n;
    __hip_bfloat16* vb   = kb + n;
    __hip_bfloat16* vt   = vb + n;
    __hip_bfloat16* ctxb = vt + n;                        // total 5n*2B = 80MB

    gemm_qkv<<<dim3(256, 8, 3), 256, 0, stream>>>(x, Wq, Wk, Wv, qb, kb, vb);
    transpose_v<<<dim3(TT / 32, BB), 256, 0, stream>>>(vb, vt);
    attn<<<dim3(64 * BB), 512, 0, stream>>>(qb, kb, vt, ctxb);
    gemm_out<<<dim3(256, 8, 1), 256, 0, stream>>>(ctxb, Wo, out);
}

// Round 14
// 299.344 us; speedup vs baseline: 1.4823x; 1.3688x over previous
//
#include <hip/hip_runtime.h>
#include <hip/hip_bf16.h>
#include <math.h>

#define D 512
#define BB 4
#define TT 4096
#define KT 32

typedef __attribute__((ext_vector_type(8))) short short8v;
typedef __attribute__((ext_vector_type(4))) short short4v;
typedef __attribute__((ext_vector_type(4))) float float4v;

__device__ inline short f2bf(float x) {
    __hip_bfloat16 h = __float2bfloat16(x);
    return *reinterpret_cast<short*>(&h);
}

// ============ QKV projection: C[t][e] = alpha * sum_d x[t][d] * W[e][d], bf16 out ============
__global__ __launch_bounds__(256) void gemm_qkv(
    const float* __restrict__ x,
    const float* __restrict__ Wq, const float* __restrict__ Wk, const float* __restrict__ Wv,
    __hip_bfloat16* __restrict__ q, __hip_bfloat16* __restrict__ k, __hip_bfloat16* __restrict__ v)
{
    const float* W; __hip_bfloat16* C; float alpha;
    if (blockIdx.z == 0)      { W = Wq; C = q; alpha = 0.044194173824159216f; } // fold 1/sqrt(512)
    else if (blockIdx.z == 1) { W = Wk; C = k; alpha = 1.f; }
    else                      { W = Wv; C = v; alpha = 1.f; }

    __shared__ short As[64][72];   // +8 bf16 pad -> conflict-floor b128 reads
    __shared__ short Bs[64][72];
    const int tid = threadIdx.x;
    const int m0 = blockIdx.x * 64, n0 = blockIdx.y * 64;
    const int w = tid >> 6, lane = tid & 63, lm = lane & 15, g = lane >> 4;

    float4v acc[4];
    #pragma unroll
    for (int i = 0; i < 4; ++i) acc[i] = (float4v){0.f,0.f,0.f,0.f};

    for (int k0 = 0; k0 < 512; k0 += 64) {
        __syncthreads();
        #pragma unroll
        for (int u = 0; u < 4; ++u) {          // stage A (x), convert f32->bf16
            int ch = tid + 256*u;
            int r = ch >> 4, c = (ch & 15) * 4;
            float4 xv = *reinterpret_cast<const float4*>(x + (size_t)(m0 + r)*512 + k0 + c);
            short4v sv = { f2bf(xv.x), f2bf(xv.y), f2bf(xv.z), f2bf(xv.w) };
            *reinterpret_cast<short4v*>(&As[r][c]) = sv;
        }
        #pragma unroll
        for (int u = 0; u < 4; ++u) {          // stage B (W rows)
            int ch = tid + 256*u;
            int r = ch >> 4, c = (ch & 15) * 4;
            float4 wv = *reinterpret_cast<const float4*>(W + (size_t)(n0 + r)*512 + k0 + c);
            short4v sv = { f2bf(wv.x), f2bf(wv.y), f2bf(wv.z), f2bf(wv.w) };
            *reinterpret_cast<short4v*>(&Bs[r][c]) = sv;
        }
        __syncthreads();
        #pragma unroll
        for (int ks = 0; ks < 2; ++ks) {
            short8v a = *reinterpret_cast<const short8v*>(&As[16*w + lm][ks*32 + 8*g]);
            #pragma unroll
            for (int nt = 0; nt < 4; ++nt) {
                short8v bv = *reinterpret_cast<const short8v*>(&Bs[16*nt + lm][ks*32 + 8*g]);
                acc[nt] = __builtin_amdgcn_mfma_f32_16x16x32_bf16(a, bv, acc[nt], 0, 0, 0);
            }
        }
    }
    #pragma unroll
    for (int nt = 0; nt < 4; ++nt)
        #pragma unroll
        for (int r = 0; r < 4; ++r) {
            int row = m0 + 16*w + 4*g + r;     // D: row = 4*(lane>>4)+reg, col = lane&15
            int col = n0 + 16*nt + lm;
            C[(size_t)row*512 + col] = __float2bfloat16(acc[nt][r] * alpha);
        }
}

// ============ V transpose with sigma-permuted columns ============
// vt[b][d][32-block of t, order pos(tau)]: pos(tau) = 8*((tau&15)>>2) + (tau&3) + 4*(tau>>4)
// -> position 8g+e within a 32-key block holds key sigma(g,e) = {4g+e, 16+4g+(e-4)}.
__global__ __launch_bounds__(256) void transpose_v(
    const __hip_bfloat16* __restrict__ vin, __hip_bfloat16* __restrict__ vout)
{
    const int tid = threadIdx.x;
    const int b = blockIdx.y;
    const int t = blockIdx.x * 32 + (tid & 31);
    const int tau = t & 31;
    const int tp = (t & ~31) + 8*((tau & 15) >> 2) + (tau & 3) + 4*(tau >> 4);
    const short* src = (const short*)vin + (size_t)(b*TT + t)*D;
    short* dst = (short*)vout + (size_t)b*D*TT;
    #pragma unroll
    for (int u = 0; u < 8; ++u) {
        int cf = (tid >> 5) + 8*u;             // 0..63 (16B chunk within row)
        short8v vv = *reinterpret_cast<const short8v*>(src + cf*8);
        #pragma unroll
        for (int i = 0; i < 8; ++i)
            dst[(size_t)(cf*8 + i)*TT + tp] = vv[i];
    }
}

// ============ Flash attention, split-K + triangle pairing, QB=64 ============
// 256 blocks = (32 pairs x 2 key-halves x 4 batches). Block (pr,s): phase0 = q-tile pr,
// phase1 = q-tile 63-pr; in each phase it processes the s-half of that tile's key range
// (s=0: tiles [0,qb+1), s=1: tiles [qb+1,2qb+2)) -> every block runs exactly 65 tiles.
// 8 waves = 4 q-groups x 2 d-halves: each tile's 64KB staging serves 64 q-rows (2x R13's
// work per LDS byte). Output: UNNORMALIZED U = sum e^{s-m} V (f32) + per-row (m, l);
// merge_halves combines the two key-halves. All inner-loop machinery (dbuf K+V DMA with
// source-XOR swizzles, pointer-toggle addressing, O^T PV, defer-max, per-lane l) is
// R11/R13-verbatim. Fully-masked rows (qb=0,s=1) handled by gating exp to 0.
__global__ __launch_bounds__(512, 1) void attn_split(
    const __hip_bfloat16* __restrict__ qg, const __hip_bfloat16* __restrict__ kg,
    const __hip_bfloat16* __restrict__ vtg,
    float* __restrict__ Ua, float* __restrict__ Ub,
    float* __restrict__ ma, float* __restrict__ la,
    float* __restrict__ mb, float* __restrict__ lb)
{
    __shared__ short Ks[2][KT][512];           // 64KB; row r chunk c holds K chunk c^(4*(r&15))
    __shared__ short Vs[2][512][32];           // 64KB; row d chunk c holds vt chunk c^((d>>1)&3)

    const int tid = threadIdx.x;
    const int w = tid >> 6, lane = tid & 63, lm = lane & 15, g = lane >> 4;
    const int qgp = w & 3, dh = w >> 2;        // q-group 0..3, d-half 0..1
    const int idx = blockIdx.x;
    const int b  = idx & 3;                    // batch -> XCD spread
    const int u  = idx >> 2;
    const int pr = u >> 1;                     // pair index 0..31
    const int s  = u & 1;                      // key-half

    const short* qp = (const short*)qg  + (size_t)b*TT*D;
    const short* kp = (const short*)kg  + (size_t)b*TT*D;
    const short* vp = (const short*)vtg + (size_t)b*D*TT;

    float* Uo = s ? Ub : Ua;
    float* mo = s ? mb : ma;
    float* lo = s ? lb : la;

    const int vswz = (lane & 3) ^ ((lane >> 3) & 3);   // V stage: source chunk for this lane

    // per-lane LDS base pointers (element = short)
    const short* k0p = &Ks[0][lm][g*8];        // QK read: kc + 32*(s^lm); second subtile +8192
    const short* k1p = &Ks[1][lm][g*8];
    const int vcid = g ^ ((lm >> 1) & 3);
    const short* v0p = &Vs[0][256*dh + lm][vcid*8];    // PV read: vc + dt*512 (literal)
    const short* v1p = &Vs[1][256*dh + lm][vcid*8];

    // stage tile T (global index) into buffer BUF; 8 waves split the 64 DMA instrs
    #define STAGE_KV(T, BUF) do {                                                  \
        const short* kt_ = kp + (size_t)(T) * KT * D;                              \
        const int ksv_ = (T) * KT;                                                 \
        _Pragma("unroll")                                                          \
        for (int i_ = 0; i_ < 4; ++i_) {                                           \
            int r_ = 4*w + i_;                                                     \
            int c_ = (lane ^ ((r_ & 15) << 2)) & 63;                               \
            __builtin_amdgcn_global_load_lds(                                      \
                (const __attribute__((address_space(1))) void*)(kt_ + (size_t)r_*D + c_*8), \
                (__attribute__((address_space(3))) void*)(&Ks[BUF][r_][0]),        \
                16, 0, 0);                                                         \
        }                                                                          \
        _Pragma("unroll")                                                          \
        for (int i_ = 0; i_ < 4; ++i_) {                                           \
            int d0_ = 64*w + 16*i_;                                                \
            int row_ = d0_ + (lane >> 2);                                          \
            __builtin_amdgcn_global_load_lds(                                      \
                (const __attribute__((address_space(1))) void*)(vp + (size_t)row_*TT + ksv_ + vswz*8), \
                (__attribute__((address_space(3))) void*)(&Vs[BUF][d0_][0]),       \
                16, 0, 0);                                                         \
        }                                                                          \
    } while (0)

    #pragma unroll 1
    for (int phase = 0; phase < 2; ++phase) {
        const int qb = phase ? (63 - pr) : pr;
        const int qbase = qb * 64;
        const int qrow  = qbase + 16*qgp + lm;
        const int t0  = s ? (qb + 1) : 0;      // this block's key-half start tile
        const int cnt = qb + 1;                // tiles in this half

        // hoist Q fragments for this phase: lane (g,lm) holds Q[qrow][32s+8g .. +8]
        short8v qf[16];
        #pragma unroll
        for (int ss = 0; ss < 16; ++ss)
            qf[ss] = *reinterpret_cast<const short8v*>(qp + (size_t)qrow*D + 32*ss + 8*g);

        float4v acc[16];                       // O^T: col=q=lm, rows=dims 256*dh+16*dt+4g+r
        #pragma unroll
        for (int i = 0; i < 16; ++i) acc[i] = (float4v){0.f,0.f,0.f,0.f};
        float m_r = -INFINITY, l_par = 0.f;    // l_par: this lane's 8-kj partial sum

        __syncthreads();                       // prev phase's LDS reads done before re-staging
        STAGE_KV(t0, 0);

        for (int i = 0; i < cnt; ++i) {
            const int t = t0 + i;
            const int ks0 = t * KT;
            __syncthreads();                   // own vmcnt drained pre-barrier -> stage(i)
                                               // landed for all waves; reads of i-1 done
            if (i + 1 < cnt) STAGE_KV(t + 1, (i + 1) & 1);

            const short* kc = (i & 1) ? k1p : k0p;
            const short* vc = (i & 1) ? v1p : v0p;

            // S^T[kj][q]: 4 independent 8-deep MFMA chains
            float4v s0a = (float4v){0.f,0.f,0.f,0.f}, s0b = (float4v){0.f,0.f,0.f,0.f};
            float4v s1a = (float4v){0.f,0.f,0.f,0.f}, s1b = (float4v){0.f,0.f,0.f,0.f};
            #pragma unroll
            for (int ss = 0; ss < 16; ++ss) {
                int off = (ss ^ lm) << 5;      // shorts: 32*(ss^lm)
                short8v a0 = *reinterpret_cast<const short8v*>(kc + off);
                short8v a1 = *reinterpret_cast<const short8v*>(kc + off + 8192);
                if (ss & 1) {
                    s0b = __builtin_amdgcn_mfma_f32_16x16x32_bf16(a0, qf[ss], s0b, 0, 0, 0);
                    s1b = __builtin_amdgcn_mfma_f32_16x16x32_bf16(a1, qf[ss], s1b, 0, 0, 0);
                } else {
                    s0a = __builtin_amdgcn_mfma_f32_16x16x32_bf16(a0, qf[ss], s0a, 0, 0, 0);
                    s1a = __builtin_amdgcn_mfma_f32_16x16x32_bf16(a1, qf[ss], s1a, 0, 0, 0);
                }
            }
            float4v s0, s1;
            #pragma unroll
            for (int r = 0; r < 4; ++r) { s0[r] = s0a[r] + s0b[r]; s1[r] = s1a[r] + s1b[r]; }

            // causal mask; lane holds kj = ks0 + sigma(g,e) for q = qrow
            float p[8];
            #pragma unroll
            for (int r = 0; r < 4; ++r) {
                int kj0 = ks0 + 4*g + r;
                p[r]     = (kj0      <= qrow) ? s0[r] : -3.0e38f;
                p[r + 4] = (kj0 + 16 <= qrow) ? s1[r] : -3.0e38f;
            }
            float mx = p[0];
            #pragma unroll
            for (int i2 = 1; i2 < 8; ++i2) mx = fmaxf(mx, p[i2]);

            // defer-max: row-max shuffles + rescale only when slack exceeded (or first tile)
            if (!__all(mx <= m_r + 8.f)) {
                float mrow = fmaxf(mx, __shfl_xor(mx, 16));
                mrow = fmaxf(mrow, __shfl_xor(mrow, 32));
                mrow = fmaxf(mrow, m_r);
                float corr = __expf(m_r - mrow);   // first tile: expf(-inf)=0
                m_r = mrow;
                l_par *= corr;
                #pragma unroll
                for (int dt = 0; dt < 16; ++dt) {
                    acc[dt][0] *= corr; acc[dt][1] *= corr;
                    acc[dt][2] *= corr; acc[dt][3] *= corr;
                }
            }
            // gated exp: fully-masked entries (incl. all-masked rows where m_r==-3e38) -> 0
            #pragma unroll
            for (int i2 = 0; i2 < 8; ++i2) {
                float e = __expf(p[i2] - m_r);
                p[i2] = (p[i2] > -1.0e37f) ? e : 0.f;
                l_par += p[i2];
            }

            // P fragment (lane-local): B-operand elems = P[q=lm][sigma(g,e)], values <= e^8
            short8v pf;
            #pragma unroll
            for (int i2 = 0; i2 < 8; ++i2) pf[i2] = f2bf(p[i2]);

            // PV (O^T): A = V^T rows of this wave's d-half, literal offsets, B = pf
            #pragma unroll
            for (int dt = 0; dt < 16; ++dt) {
                short8v vf = *reinterpret_cast<const short8v*>(vc + dt*512);
                acc[dt] = __builtin_amdgcn_mfma_f32_16x16x32_bf16(vf, pf, acc[dt], 0, 0, 0);
            }
        }

        // phase epilogue: reduce l across the row's 4 g-lanes; store UNNORMALIZED U + (m,l)
        float l = l_par + __shfl_xor(l_par, 16);
        l += __shfl_xor(l, 32);
        const int orow = qbase + 16*qgp + lm;
        float* up = Uo + (size_t)(b*TT + orow)*D + 256*dh;
        #pragma unroll
        for (int dt = 0; dt < 16; ++dt) {
            float4 o = { acc[dt][0], acc[dt][1], acc[dt][2], acc[dt][3] };
            *reinterpret_cast<float4*>(up + 16*dt + 4*g) = o;
        }
        if (dh == 0 && g == 0) {               // one writer per row
            mo[(size_t)b*TT + orow] = m_r;
            lo[(size_t)b*TT + orow] = l;
        }
    }
    #undef STAGE_KV
}

// ============ Merge the two key-halves: O = (Ua*wa + Ub*wb) / (la*wa + lb*wb) ============
__global__ __launch_bounds__(256) void merge_halves(
    const float* __restrict__ Ua, const float* __restrict__ Ub,
    const float* __restrict__ ma, const float* __restrict__ la,
    const float* __restrict__ mb, const float* __restrict__ lb,
    __hip_bfloat16* __restrict__ ctx)
{
    const int tid = threadIdx.x;
    const int row = blockIdx.x * 2 + (tid >> 7);       // global row in [0, BB*TT)
    const int c = (tid & 127) * 4;
    float ma_ = ma[row], la_ = la[row], mb_ = mb[row], lb_ = lb[row];
    float ms = fmaxf(ma_, mb_);
    float wa = __expf(ma_ - ms), wb = __expf(mb_ - ms);
    float inv = 1.f / (la_*wa + lb_*wb);
    wa *= inv; wb *= inv;
    float4 av = *reinterpret_cast<const float4*>(Ua + (size_t)row*D + c);
    float4 bv = *reinterpret_cast<const float4*>(Ub + (size_t)row*D + c);
    short4v o = { f2bf(av.x*wa + bv.x*wb), f2bf(av.y*wa + bv.y*wb),
                  f2bf(av.z*wa + bv.z*wb), f2bf(av.w*wa + bv.w*wb) };
    *reinterpret_cast<short4v*>((short*)ctx + (size_t)row*D + c) = o;
}

// ============ Output projection: d_out[t][e] = sum_d ctx[t][d] * Wo[e][d], f32 out ============
__global__ __launch_bounds__(256) void gemm_out(
    const __hip_bfloat16* __restrict__ Ab, const float* __restrict__ W,
    float* __restrict__ Cf)
{
    __shared__ short As[64][72];
    __shared__ short Bs[64][72];
    const int tid = threadIdx.x;
    const int m0 = blockIdx.x * 64, n0 = blockIdx.y * 64;
    const int w = tid >> 6, lane = tid & 63, lm = lane & 15, g = lane >> 4;
    const short* Ap = (const short*)Ab;

    float4v acc[4];
    #pragma unroll
    for (int i = 0; i < 4; ++i) acc[i] = (float4v){0.f,0.f,0.f,0.f};

    for (int k0 = 0; k0 < 512; k0 += 64) {
        __syncthreads();
        #pragma unroll
        for (int u = 0; u < 2; ++u) {          // stage A (bf16 ctx)
            int ch = tid + 256*u;
            int r = ch >> 3, c = (ch & 7) * 8;
            *reinterpret_cast<short8v*>(&As[r][c]) =
                *reinterpret_cast<const short8v*>(Ap + (size_t)(m0 + r)*512 + k0 + c);
        }
        #pragma unroll
        for (int u = 0; u < 4; ++u) {          // stage B (Wo f32 -> bf16)
            int ch = tid + 256*u;
            int r = ch >> 4, c = (ch & 15) * 4;
            float4 wv = *reinterpret_cast<const float4*>(W + (size_t)(n0 + r)*512 + k0 + c);
            short4v sv = { f2bf(wv.x), f2bf(wv.y), f2bf(wv.z), f2bf(wv.w) };
            *reinterpret_cast<short4v*>(&Bs[r][c]) = sv;
        }
        __syncthreads();
        #pragma unroll
        for (int ks = 0; ks < 2; ++ks) {
            short8v a = *reinterpret_cast<const short8v*>(&As[16*w + lm][ks*32 + 8*g]);
            #pragma unroll
            for (int nt = 0; nt < 4; ++nt) {
                short8v bv = *reinterpret_cast<const short8v*>(&Bs[16*nt + lm][ks*32 + 8*g]);
                acc[nt] = __builtin_amdgcn_mfma_f32_16x16x32_bf16(a, bv, acc[nt], 0, 0, 0);
            }
        }
    }
    #pragma unroll
    for (int nt = 0; nt < 4; ++nt)
        #pragma unroll
        for (int r = 0; r < 4; ++r) {
            int row = m0 + 16*w + 4*g + r;
            int col = n0 + 16*nt + lm;
            Cf[(size_t)row*512 + col] = acc[nt][r];
        }
}

extern "C" void kernel_launch(void* const* d_in, const int* in_sizes, int n_in,
                              void* d_out, int out_size, void* d_ws, size_t ws_size,
                              hipStream_t stream) {
    const float* x  = (const float*)d_in[0];
    const float* Wq = (const float*)d_in[1];
    const float* Wk = (const float*)d_in[2];
    const float* Wv = (const float*)d_in[3];
    const float* Wo = (const float*)d_in[4];
    float* out = (float*)d_out;

    const size_t n = (size_t)BB * TT * D;                 // 8.4M elems
    __hip_bfloat16* qb_  = (__hip_bfloat16*)d_ws;
    __hip_bfloat16* kb_  = qb_ + n;
    __hip_bfloat16* vb_  = kb_ + n;
    __hip_bfloat16* vt_  = vb_ + n;
    __hip_bfloat16* ctxb = vt_ + n;                       // [0, 5n) bf16 = 84MB
    float* Ub  = (float*)(ctxb + n);                      // 34MB
    float* ma_ = Ub + n;                                  // 4 x 64KB
    float* la_ = ma_ + (size_t)BB*TT;
    float* mb_ = la_ + (size_t)BB*TT;
    float* lb_ = mb_ + (size_t)BB*TT;
    float* Ua  = out;                                     // d_out as scratch (overwritten by gemm_out)

    gemm_qkv<<<dim3(256, 8, 3), 256, 0, stream>>>(x, Wq, Wk, Wv, qb_, kb_, vb_);
    transpose_v<<<dim3(TT / 32, BB), 256, 0, stream>>>(vb_, vt_);
    attn_split<<<dim3(64 * BB), 512, 0, stream>>>(qb_, kb_, vt_, Ua, Ub, ma_, la_, mb_, lb_);
    merge_halves<<<dim3(BB * TT / 2), 256, 0, stream>>>(Ua, Ub, ma_, la_, mb_, lb_, ctxb);
    gemm_out<<<dim3(256, 8, 1), 256, 0, stream>>>(ctxb, Wo, out);
}

// Round 15
// 259.602 us; speedup vs baseline: 1.7092x; 1.1531x over previous
//
#include <hip/hip_runtime.h>
#include <hip/hip_bf16.h>
#include <math.h>

#define D 512
#define BB 4
#define TT 4096
#define KT 32

typedef __attribute__((ext_vector_type(8))) short short8v;
typedef __attribute__((ext_vector_type(4))) short short4v;
typedef __attribute__((ext_vector_type(4))) float float4v;

__device__ inline short f2bf(float x) {
    __hip_bfloat16 h = __float2bfloat16(x);
    return *reinterpret_cast<short*>(&h);
}
__device__ inline float bf2f(short s) {
    __hip_bfloat16 h = *reinterpret_cast<__hip_bfloat16*>(&s);
    return __bfloat162float(h);
}

// ============ QKV projection: C[t][e] = alpha * sum_d x[t][d] * W[e][d], bf16 out ============
__global__ __launch_bounds__(256) void gemm_qkv(
    const float* __restrict__ x,
    const float* __restrict__ Wq, const float* __restrict__ Wk, const float* __restrict__ Wv,
    __hip_bfloat16* __restrict__ q, __hip_bfloat16* __restrict__ k, __hip_bfloat16* __restrict__ v)
{
    const float* W; __hip_bfloat16* C; float alpha;
    if (blockIdx.z == 0)      { W = Wq; C = q; alpha = 0.044194173824159216f; } // fold 1/sqrt(512)
    else if (blockIdx.z == 1) { W = Wk; C = k; alpha = 1.f; }
    else                      { W = Wv; C = v; alpha = 1.f; }

    __shared__ short As[64][72];   // +8 bf16 pad -> conflict-floor b128 reads
    __shared__ short Bs[64][72];
    const int tid = threadIdx.x;
    const int m0 = blockIdx.x * 64, n0 = blockIdx.y * 64;
    const int w = tid >> 6, lane = tid & 63, lm = lane & 15, g = lane >> 4;

    float4v acc[4];
    #pragma unroll
    for (int i = 0; i < 4; ++i) acc[i] = (float4v){0.f,0.f,0.f,0.f};

    for (int k0 = 0; k0 < 512; k0 += 64) {
        __syncthreads();
        #pragma unroll
        for (int u = 0; u < 4; ++u) {          // stage A (x), convert f32->bf16
            int ch = tid + 256*u;
            int r = ch >> 4, c = (ch & 15) * 4;
            float4 xv = *reinterpret_cast<const float4*>(x + (size_t)(m0 + r)*512 + k0 + c);
            short4v sv = { f2bf(xv.x), f2bf(xv.y), f2bf(xv.z), f2bf(xv.w) };
            *reinterpret_cast<short4v*>(&As[r][c]) = sv;
        }
        #pragma unroll
        for (int u = 0; u < 4; ++u) {          // stage B (W rows)
            int ch = tid + 256*u;
            int r = ch >> 4, c = (ch & 15) * 4;
            float4 wv = *reinterpret_cast<const float4*>(W + (size_t)(n0 + r)*512 + k0 + c);
            short4v sv = { f2bf(wv.x), f2bf(wv.y), f2bf(wv.z), f2bf(wv.w) };
            *reinterpret_cast<short4v*>(&Bs[r][c]) = sv;
        }
        __syncthreads();
        #pragma unroll
        for (int ks = 0; ks < 2; ++ks) {
            short8v a = *reinterpret_cast<const short8v*>(&As[16*w + lm][ks*32 + 8*g]);
            #pragma unroll
            for (int nt = 0; nt < 4; ++nt) {
                short8v bv = *reinterpret_cast<const short8v*>(&Bs[16*nt + lm][ks*32 + 8*g]);
                acc[nt] = __builtin_amdgcn_mfma_f32_16x16x32_bf16(a, bv, acc[nt], 0, 0, 0);
            }
        }
    }
    #pragma unroll
    for (int nt = 0; nt < 4; ++nt)
        #pragma unroll
        for (int r = 0; r < 4; ++r) {
            int row = m0 + 16*w + 4*g + r;     // D: row = 4*(lane>>4)+reg, col = lane&15
            int col = n0 + 16*nt + lm;
            C[(size_t)row*512 + col] = __float2bfloat16(acc[nt][r] * alpha);
        }
}

// ============ V transpose with sigma-permuted columns ============
// vt[b][d][32-block of t, order pos(tau)]: pos(tau) = 8*((tau&15)>>2) + (tau&3) + 4*(tau>>4)
// -> position 8g+e within a 32-key block holds key sigma(g,e) = {4g+e, 16+4g+(e-4)}.
__global__ __launch_bounds__(256) void transpose_v(
    const __hip_bfloat16* __restrict__ vin, __hip_bfloat16* __restrict__ vout)
{
    const int tid = threadIdx.x;
    const int b = blockIdx.y;
    const int t = blockIdx.x * 32 + (tid & 31);
    const int tau = t & 31;
    const int tp = (t & ~31) + 8*((tau & 15) >> 2) + (tau & 3) + 4*(tau >> 4);
    const short* src = (const short*)vin + (size_t)(b*TT + t)*D;
    short* dst = (short*)vout + (size_t)b*D*TT;
    #pragma unroll
    for (int u = 0; u < 8; ++u) {
        int cf = (tid >> 5) + 8*u;             // 0..63 (16B chunk within row)
        short8v vv = *reinterpret_cast<const short8v*>(src + cf*8);
        #pragma unroll
        for (int i = 0; i < 8; ++i)
            dst[(size_t)(cf*8 + i)*TT + tp] = vv[i];
    }
}

// ============ Flash attention, QB=128, 4-way split-K + triangle pairing ============
// 256 blocks = (16 pairs x 4 key-quarters x 4 batches). Block (pr,s): phase0 = q-tile pr,
// phase1 = q-tile 31-pr; quarter s covers k-tiles [s(qb+1), (s+1)(qb+1)) -> every block
// runs exactly 33 tiles. 8 waves = 8 q-groups, each owning 16 q-rows x FULL 512 dims
// (acc = 32 float4v): zero d-redundancy, so each 64KB-staged tile serves 128 q-rows.
// Output: UNNORMALIZED U (bf16) + per-row (m, l) per quarter; merge_quads combines.
// Inner machinery R14-verbatim: dbuf K+V DMA with source-XOR swizzles, pointer-toggle,
// O^T PV, defer-max (THR=8), per-lane partial l, gated exp for fully-masked tiles.
__global__ __launch_bounds__(512, 1) void attn_split(
    const __hip_bfloat16* __restrict__ qg, const __hip_bfloat16* __restrict__ kg,
    const __hip_bfloat16* __restrict__ vtg,
    __hip_bfloat16* __restrict__ U0, __hip_bfloat16* __restrict__ U1,
    __hip_bfloat16* __restrict__ U2, __hip_bfloat16* __restrict__ U3,
    float* __restrict__ mArr, float* __restrict__ lArr)
{
    __shared__ short Ks[2][KT][512];           // 64KB; row r chunk c holds K chunk c^(4*(r&15))
    __shared__ short Vs[2][512][32];           // 64KB; row d chunk c holds vt chunk c^((d>>1)&3)

    const int tid = threadIdx.x;
    const int w = tid >> 6, lane = tid & 63, lm = lane & 15, g = lane >> 4;
    const int qgp = w;                         // q-group 0..7 (full-d wave)
    const int idx = blockIdx.x;
    const int b  = idx & 3;                    // batch -> XCD spread
    const int u  = idx >> 2;
    const int pr = u >> 2;                     // pair index 0..15
    const int s  = u & 3;                      // key-quarter

    const short* qp = (const short*)qg  + (size_t)b*TT*D;
    const short* kp = (const short*)kg  + (size_t)b*TT*D;
    const short* vp = (const short*)vtg + (size_t)b*D*TT;

    short* Uo = (short*)((s == 0) ? U0 : (s == 1) ? U1 : (s == 2) ? U2 : U3);
    float* mo = mArr + (size_t)s * BB * TT;
    float* lo = lArr + (size_t)s * BB * TT;

    const int vswz = (lane & 3) ^ ((lane >> 3) & 3);   // V stage: source chunk for this lane

    // per-lane LDS base pointers (element = short)
    const short* k0p = &Ks[0][lm][g*8];        // QK read: kc + 32*(ss^lm); second subtile +8192
    const short* k1p = &Ks[1][lm][g*8];
    const int vcid = g ^ ((lm >> 1) & 3);
    const short* v0p = &Vs[0][lm][vcid*8];     // PV read: vc + dt*512 (literal), dt 0..31
    const short* v1p = &Vs[1][lm][vcid*8];

    // stage k-tile T (global index) into buffer BUF; 8 waves split the 64 DMA instrs
    #define STAGE_KV(T, BUF) do {                                                  \
        const short* kt_ = kp + (size_t)(T) * KT * D;                              \
        const int ksv_ = (T) * KT;                                                 \
        _Pragma("unroll")                                                          \
        for (int i_ = 0; i_ < 4; ++i_) {                                           \
            int r_ = 4*w + i_;                                                     \
            int c_ = (lane ^ ((r_ & 15) << 2)) & 63;                               \
            __builtin_amdgcn_global_load_lds(                                      \
                (const __attribute__((address_space(1))) void*)(kt_ + (size_t)r_*D + c_*8), \
                (__attribute__((address_space(3))) void*)(&Ks[BUF][r_][0]),        \
                16, 0, 0);                                                         \
        }                                                                          \
        _Pragma("unroll")                                                          \
        for (int i_ = 0; i_ < 4; ++i_) {                                           \
            int d0_ = 64*w + 16*i_;                                                \
            int row_ = d0_ + (lane >> 2);                                          \
            __builtin_amdgcn_global_load_lds(                                      \
                (const __attribute__((address_space(1))) void*)(vp + (size_t)row_*TT + ksv_ + vswz*8), \
                (__attribute__((address_space(3))) void*)(&Vs[BUF][d0_][0]),       \
                16, 0, 0);                                                         \
        }                                                                          \
    } while (0)

    #pragma unroll 1
    for (int phase = 0; phase < 2; ++phase) {
        const int qb = phase ? (31 - pr) : pr;
        const int qbase = qb * 128;
        const int qrow  = qbase + 16*qgp + lm;
        const int t0  = s * (qb + 1);          // this quarter's start k-tile
        const int cnt = qb + 1;                // k-tiles in this quarter

        // hoist Q fragments for this phase: lane (g,lm) holds Q[qrow][32ss+8g .. +8]
        short8v qf[16];
        #pragma unroll
        for (int ss = 0; ss < 16; ++ss)
            qf[ss] = *reinterpret_cast<const short8v*>(qp + (size_t)qrow*D + 32*ss + 8*g);

        float4v acc[32];                       // O^T: col=q=lm, rows=dims 16*dt+4g+r
        #pragma unroll
        for (int i = 0; i < 32; ++i) acc[i] = (float4v){0.f,0.f,0.f,0.f};
        float m_r = -INFINITY, l_par = 0.f;    // l_par: this lane's 8-kj partial sum

        __syncthreads();                       // prev phase's LDS reads done before re-staging
        STAGE_KV(t0, 0);

        for (int i = 0; i < cnt; ++i) {
            const int t = t0 + i;
            const int ks0 = t * KT;
            __syncthreads();                   // own vmcnt drained pre-barrier -> stage(i)
                                               // landed for all waves; reads of i-1 done
            if (i + 1 < cnt) STAGE_KV(t + 1, (i + 1) & 1);

            const short* kc = (i & 1) ? k1p : k0p;
            const short* vc = (i & 1) ? v1p : v0p;

            // S^T[kj][q]: 4 independent 8-deep MFMA chains
            float4v s0a = (float4v){0.f,0.f,0.f,0.f}, s0b = (float4v){0.f,0.f,0.f,0.f};
            float4v s1a = (float4v){0.f,0.f,0.f,0.f}, s1b = (float4v){0.f,0.f,0.f,0.f};
            #pragma unroll
            for (int ss = 0; ss < 16; ++ss) {
                int off = (ss ^ lm) << 5;      // shorts: 32*(ss^lm)
                short8v a0 = *reinterpret_cast<const short8v*>(kc + off);
                short8v a1 = *reinterpret_cast<const short8v*>(kc + off + 8192);
                if (ss & 1) {
                    s0b = __builtin_amdgcn_mfma_f32_16x16x32_bf16(a0, qf[ss], s0b, 0, 0, 0);
                    s1b = __builtin_amdgcn_mfma_f32_16x16x32_bf16(a1, qf[ss], s1b, 0, 0, 0);
                } else {
                    s0a = __builtin_amdgcn_mfma_f32_16x16x32_bf16(a0, qf[ss], s0a, 0, 0, 0);
                    s1a = __builtin_amdgcn_mfma_f32_16x16x32_bf16(a1, qf[ss], s1a, 0, 0, 0);
                }
            }
            float4v s0, s1;
            #pragma unroll
            for (int r = 0; r < 4; ++r) { s0[r] = s0a[r] + s0b[r]; s1[r] = s1a[r] + s1b[r]; }

            // causal mask; lane holds kj = ks0 + sigma(g,e) for q = qrow
            float p[8];
            #pragma unroll
            for (int r = 0; r < 4; ++r) {
                int kj0 = ks0 + 4*g + r;
                p[r]     = (kj0      <= qrow) ? s0[r] : -3.0e38f;
                p[r + 4] = (kj0 + 16 <= qrow) ? s1[r] : -3.0e38f;
            }
            float mx = p[0];
            #pragma unroll
            for (int i2 = 1; i2 < 8; ++i2) mx = fmaxf(mx, p[i2]);

            // defer-max: row-max shuffles + rescale only when slack exceeded (or first tile)
            if (!__all(mx <= m_r + 8.f)) {
                float mrow = fmaxf(mx, __shfl_xor(mx, 16));
                mrow = fmaxf(mrow, __shfl_xor(mrow, 32));
                mrow = fmaxf(mrow, m_r);
                float corr = __expf(m_r - mrow);   // first tile: expf(-inf)=0
                m_r = mrow;
                l_par *= corr;
                #pragma unroll
                for (int dt = 0; dt < 32; ++dt) {
                    acc[dt][0] *= corr; acc[dt][1] *= corr;
                    acc[dt][2] *= corr; acc[dt][3] *= corr;
                }
            }
            // gated exp: fully-masked entries (incl. all-masked rows where m_r==-3e38) -> 0
            #pragma unroll
            for (int i2 = 0; i2 < 8; ++i2) {
                float e = __expf(p[i2] - m_r);
                p[i2] = (p[i2] > -1.0e37f) ? e : 0.f;
                l_par += p[i2];
            }

            // P fragment (lane-local): B-operand elems = P[q=lm][sigma(g,e)], values <= e^8
            short8v pf;
            #pragma unroll
            for (int i2 = 0; i2 < 8; ++i2) pf[i2] = f2bf(p[i2]);

            // PV (O^T): A = V^T rows (full 512 dims), literal offsets, B = pf
            #pragma unroll
            for (int dt = 0; dt < 32; ++dt) {
                short8v vf = *reinterpret_cast<const short8v*>(vc + dt*512);
                acc[dt] = __builtin_amdgcn_mfma_f32_16x16x32_bf16(vf, pf, acc[dt], 0, 0, 0);
            }
        }

        // phase epilogue: reduce l across the row's 4 g-lanes; store UNNORMALIZED U + (m,l)
        float l = l_par + __shfl_xor(l_par, 16);
        l += __shfl_xor(l, 32);
        const int orow = qbase + 16*qgp + lm;
        short* up = Uo + (size_t)(b*TT + orow)*D;
        #pragma unroll
        for (int dt = 0; dt < 32; ++dt) {
            short4v o = { f2bf(acc[dt][0]), f2bf(acc[dt][1]),
                          f2bf(acc[dt][2]), f2bf(acc[dt][3]) };
            *reinterpret_cast<short4v*>(up + 16*dt + 4*g) = o;
        }
        if (g == 0) {                          // one writer per row (lanes 0..15)
            mo[(size_t)b*TT + orow] = m_r;
            lo[(size_t)b*TT + orow] = l;
        }
    }
    #undef STAGE_KV
}

// ============ Merge the four key-quarters: O = sum_s U_s*w_s / sum_s l_s*w_s ============
__global__ __launch_bounds__(256) void merge_quads(
    const __hip_bfloat16* __restrict__ U0, const __hip_bfloat16* __restrict__ U1,
    const __hip_bfloat16* __restrict__ U2, const __hip_bfloat16* __restrict__ U3,
    const float* __restrict__ mArr, const float* __restrict__ lArr,
    __hip_bfloat16* __restrict__ ctx)
{
    const int BT = BB * TT;
    const int gidx = blockIdx.x * 256 + threadIdx.x;   // one thread per 8 cols
    const int row = gidx >> 6;
    const int c = (gidx & 63) * 8;
    float m0 = mArr[row], m1 = mArr[BT + row], m2 = mArr[2*BT + row], m3 = mArr[3*BT + row];
    float ms = fmaxf(fmaxf(m0, m1), fmaxf(m2, m3));
    float w0 = __expf(m0 - ms), w1 = __expf(m1 - ms);
    float w2 = __expf(m2 - ms), w3 = __expf(m3 - ms);
    float l = lArr[row]*w0 + lArr[BT + row]*w1 + lArr[2*BT + row]*w2 + lArr[3*BT + row]*w3;
    float inv = 1.f / l;
    w0 *= inv; w1 *= inv; w2 *= inv; w3 *= inv;
    size_t off = (size_t)row * D + c;
    short8v a = *reinterpret_cast<const short8v*>((const short*)U0 + off);
    short8v b = *reinterpret_cast<const short8v*>((const short*)U1 + off);
    short8v d = *reinterpret_cast<const short8v*>((const short*)U2 + off);
    short8v e = *reinterpret_cast<const short8v*>((const short*)U3 + off);
    short8v o;
    #pragma unroll
    for (int i = 0; i < 8; ++i)
        o[i] = f2bf(bf2f(a[i])*w0 + bf2f(b[i])*w1 + bf2f(d[i])*w2 + bf2f(e[i])*w3);
    *reinterpret_cast<short8v*>((short*)ctx + off) = o;
}

// ============ Output projection: d_out[t][e] = sum_d ctx[t][d] * Wo[e][d], f32 out ============
__global__ __launch_bounds__(256) void gemm_out(
    const __hip_bfloat16* __restrict__ Ab, const float* __restrict__ W,
    float* __restrict__ Cf)
{
    __shared__ short As[64][72];
    __shared__ short Bs[64][72];
    const int tid = threadIdx.x;
    const int m0 = blockIdx.x * 64, n0 = blockIdx.y * 64;
    const int w = tid >> 6, lane = tid & 63, lm = lane & 15, g = lane >> 4;
    const short* Ap = (const short*)Ab;

    float4v acc[4];
    #pragma unroll
    for (int i = 0; i < 4; ++i) acc[i] = (float4v){0.f,0.f,0.f,0.f};

    for (int k0 = 0; k0 < 512; k0 += 64) {
        __syncthreads();
        #pragma unroll
        for (int u = 0; u < 2; ++u) {          // stage A (bf16 ctx)
            int ch = tid + 256*u;
            int r = ch >> 3, c = (ch & 7) * 8;
            *reinterpret_cast<short8v*>(&As[r][c]) =
                *reinterpret_cast<const short8v*>(Ap + (size_t)(m0 + r)*512 + k0 + c);
        }
        #pragma unroll
        for (int u = 0; u < 4; ++u) {          // stage B (Wo f32 -> bf16)
            int ch = tid + 256*u;
            int r = ch >> 4, c = (ch & 15) * 4;
            float4 wv = *reinterpret_cast<const float4*>(W + (size_t)(n0 + r)*512 + k0 + c);
            short4v sv = { f2bf(wv.x), f2bf(wv.y), f2bf(wv.z), f2bf(wv.w) };
            *reinterpret_cast<short4v*>(&Bs[r][c]) = sv;
        }
        __syncthreads();
        #pragma unroll
        for (int ks = 0; ks < 2; ++ks) {
            short8v a = *reinterpret_cast<const short8v*>(&As[16*w + lm][ks*32 + 8*g]);
            #pragma unroll
            for (int nt = 0; nt < 4; ++nt) {
                short8v bv = *reinterpret_cast<const short8v*>(&Bs[16*nt + lm][ks*32 + 8*g]);
                acc[nt] = __builtin_amdgcn_mfma_f32_16x16x32_bf16(a, bv, acc[nt], 0, 0, 0);
            }
        }
    }
    #pragma unroll
    for (int nt = 0; nt < 4; ++nt)
        #pragma unroll
        for (int r = 0; r < 4; ++r) {
            int row = m0 + 16*w + 4*g + r;
            int col = n0 + 16*nt + lm;
            Cf[(size_t)row*512 + col] = acc[nt][r];
        }
}

extern "C" void kernel_launch(void* const* d_in, const int* in_sizes, int n_in,
                              void* d_out, int out_size, void* d_ws, size_t ws_size,
                              hipStream_t stream) {
    const float* x  = (const float*)d_in[0];
    const float* Wq = (const float*)d_in[1];
    const float* Wk = (const float*)d_in[2];
    const float* Wv = (const float*)d_in[3];
    const float* Wo = (const float*)d_in[4];
    float* out = (float*)d_out;

    const size_t n = (size_t)BB * TT * D;                 // 8.4M elems
    __hip_bfloat16* qb_  = (__hip_bfloat16*)d_ws;
    __hip_bfloat16* kb_  = qb_ + n;
    __hip_bfloat16* vb_  = kb_ + n;
    __hip_bfloat16* vt_  = vb_ + n;
    __hip_bfloat16* ctxb = vt_ + n;                       // [0, 5n) bf16 = 84MB
    __hip_bfloat16* U1   = ctxb + n;                      // 3 x 16.8MB bf16
    __hip_bfloat16* U2   = U1 + n;
    __hip_bfloat16* U3   = U2 + n;
    float* mArr = (float*)(U3 + n);                       // 4 x BT f32 = 1MB
    float* lArr = mArr + (size_t)4 * BB * TT;             // 4 x BT f32 = 1MB
    __hip_bfloat16* U0 = (__hip_bfloat16*)out;            // d_out as scratch (overwritten later)

    gemm_qkv<<<dim3(256, 8, 3), 256, 0, stream>>>(x, Wq, Wk, Wv, qb_, kb_, vb_);
    transpose_v<<<dim3(TT / 32, BB), 256, 0, stream>>>(vb_, vt_);
    attn_split<<<dim3(64 * BB), 512, 0, stream>>>(qb_, kb_, vt_, U0, U1, U2, U3, mArr, lArr);
    merge_quads<<<dim3(BB * TT / 4), 256, 0, stream>>>(U0, U1, U2, U3, mArr, lArr, ctxb);
    gemm_out<<<dim3(256, 8, 1), 256, 0, stream>>>(ctxb, Wo, out);
}

// Round 16
// 244.168 us; speedup vs baseline: 1.8172x; 1.0632x over previous
//
#include <hip/hip_runtime.h>
#include <hip/hip_bf16.h>
#include <math.h>

#define D 512
#define BB 4
#define TT 4096
#define KT 32

typedef __attribute__((ext_vector_type(8))) short short8v;
typedef __attribute__((ext_vector_type(4))) short short4v;
typedef __attribute__((ext_vector_type(4))) float float4v;

__device__ inline short f2bf(float x) {
    __hip_bfloat16 h = __float2bfloat16(x);
    return *reinterpret_cast<short*>(&h);
}
__device__ inline float bf2f(short s) {
    __hip_bfloat16 h = *reinterpret_cast<__hip_bfloat16*>(&s);
    return __bfloat162float(h);
}

// ============ Fused QKV projection: one x-stage feeds 3 weight matrices ============
// C_z[t][e] = alpha_z * sum_d x[t][d] * W_z[e][d], bf16 out. x staged+converted ONCE.
__global__ __launch_bounds__(256) void gemm_qkv(
    const float* __restrict__ x,
    const float* __restrict__ Wq, const float* __restrict__ Wk, const float* __restrict__ Wv,
    __hip_bfloat16* __restrict__ q, __hip_bfloat16* __restrict__ k, __hip_bfloat16* __restrict__ v)
{
    __shared__ short As[64][72];       // +8 bf16 pad -> conflict-floor b128 reads
    __shared__ short Bs[3][64][72];
    const int tid = threadIdx.x;
    const int m0 = blockIdx.x * 64, n0 = blockIdx.y * 64;
    const int w = tid >> 6, lane = tid & 63, lm = lane & 15, g = lane >> 4;

    float4v acc[3][4];
    #pragma unroll
    for (int z = 0; z < 3; ++z)
        #pragma unroll
        for (int i = 0; i < 4; ++i) acc[z][i] = (float4v){0.f,0.f,0.f,0.f};

    for (int k0 = 0; k0 < 512; k0 += 64) {
        __syncthreads();
        #pragma unroll
        for (int u = 0; u < 4; ++u) {          // stage A (x), convert f32->bf16, ONCE
            int ch = tid + 256*u;
            int r = ch >> 4, c = (ch & 15) * 4;
            float4 xv = *reinterpret_cast<const float4*>(x + (size_t)(m0 + r)*512 + k0 + c);
            short4v sv = { f2bf(xv.x), f2bf(xv.y), f2bf(xv.z), f2bf(xv.w) };
            *reinterpret_cast<short4v*>(&As[r][c]) = sv;
        }
        #pragma unroll
        for (int z = 0; z < 3; ++z) {          // stage B for all 3 weight matrices
            const float* W = (z == 0) ? Wq : (z == 1) ? Wk : Wv;
            #pragma unroll
            for (int u = 0; u < 4; ++u) {
                int ch = tid + 256*u;
                int r = ch >> 4, c = (ch & 15) * 4;
                float4 wv = *reinterpret_cast<const float4*>(W + (size_t)(n0 + r)*512 + k0 + c);
                short4v sv = { f2bf(wv.x), f2bf(wv.y), f2bf(wv.z), f2bf(wv.w) };
                *reinterpret_cast<short4v*>(&Bs[z][r][c]) = sv;
            }
        }
        __syncthreads();
        #pragma unroll
        for (int ks = 0; ks < 2; ++ks) {
            short8v a = *reinterpret_cast<const short8v*>(&As[16*w + lm][ks*32 + 8*g]);
            #pragma unroll
            for (int z = 0; z < 3; ++z)
                #pragma unroll
                for (int nt = 0; nt < 4; ++nt) {
                    short8v bv = *reinterpret_cast<const short8v*>(&Bs[z][16*nt + lm][ks*32 + 8*g]);
                    acc[z][nt] = __builtin_amdgcn_mfma_f32_16x16x32_bf16(a, bv, acc[z][nt], 0, 0, 0);
                }
        }
    }
    #pragma unroll
    for (int z = 0; z < 3; ++z) {
        __hip_bfloat16* C = (z == 0) ? q : (z == 1) ? k : v;
        const float alpha = (z == 0) ? 0.044194173824159216f : 1.f;   // fold 1/sqrt(512) into q
        #pragma unroll
        for (int nt = 0; nt < 4; ++nt)
            #pragma unroll
            for (int r = 0; r < 4; ++r) {
                int row = m0 + 16*w + 4*g + r; // D: row = 4*(lane>>4)+reg, col = lane&15
                int col = n0 + 16*nt + lm;
                C[(size_t)row*512 + col] = __float2bfloat16(acc[z][nt][r] * alpha);
            }
    }
}

// ============ V transpose with sigma-permuted columns ============
// vt[b][d][32-block of t, order pos(tau)]: pos(tau) = 8*((tau&15)>>2) + (tau&3) + 4*(tau>>4)
// -> position 8g+e within a 32-key block holds key sigma(g,e) = {4g+e, 16+4g+(e-4)}.
__global__ __launch_bounds__(256) void transpose_v(
    const __hip_bfloat16* __restrict__ vin, __hip_bfloat16* __restrict__ vout)
{
    const int tid = threadIdx.x;
    const int b = blockIdx.y;
    const int t = blockIdx.x * 32 + (tid & 31);
    const int tau = t & 31;
    const int tp = (t & ~31) + 8*((tau & 15) >> 2) + (tau & 3) + 4*(tau >> 4);
    const short* src = (const short*)vin + (size_t)(b*TT + t)*D;
    short* dst = (short*)vout + (size_t)b*D*TT;
    #pragma unroll
    for (int u = 0; u < 8; ++u) {
        int cf = (tid >> 5) + 8*u;             // 0..63 (16B chunk within row)
        short8v vv = *reinterpret_cast<const short8v*>(src + cf*8);
        #pragma unroll
        for (int i = 0; i < 8; ++i)
            dst[(size_t)(cf*8 + i)*TT + tp] = vv[i];
    }
}

// ============ Flash attention, QB=128, 4-way split-K + triangle pairing ============
// R15-verbatim structure (8 full-d waves, dbuf K+V DMA, source-XOR swizzles, pointer-
// toggle, O^T PV, defer-max, per-lane l, gated exp) + s_setprio(1) around MFMA clusters
// (T5: with 2 waves/SIMD in different phases, prioritize the wave entering MFMA).
__global__ __launch_bounds__(512, 1) void attn_split(
    const __hip_bfloat16* __restrict__ qg, const __hip_bfloat16* __restrict__ kg,
    const __hip_bfloat16* __restrict__ vtg,
    __hip_bfloat16* __restrict__ U0, __hip_bfloat16* __restrict__ U1,
    __hip_bfloat16* __restrict__ U2, __hip_bfloat16* __restrict__ U3,
    float* __restrict__ mArr, float* __restrict__ lArr)
{
    __shared__ short Ks[2][KT][512];           // 64KB; row r chunk c holds K chunk c^(4*(r&15))
    __shared__ short Vs[2][512][32];           // 64KB; row d chunk c holds vt chunk c^((d>>1)&3)

    const int tid = threadIdx.x;
    const int w = tid >> 6, lane = tid & 63, lm = lane & 15, g = lane >> 4;
    const int qgp = w;                         // q-group 0..7 (full-d wave)
    const int idx = blockIdx.x;
    const int b  = idx & 3;                    // batch -> XCD spread
    const int u  = idx >> 2;
    const int pr = u >> 2;                     // pair index 0..15
    const int s  = u & 3;                      // key-quarter

    const short* qp = (const short*)qg  + (size_t)b*TT*D;
    const short* kp = (const short*)kg  + (size_t)b*TT*D;
    const short* vp = (const short*)vtg + (size_t)b*D*TT;

    short* Uo = (short*)((s == 0) ? U0 : (s == 1) ? U1 : (s == 2) ? U2 : U3);
    float* mo = mArr + (size_t)s * BB * TT;
    float* lo = lArr + (size_t)s * BB * TT;

    const int vswz = (lane & 3) ^ ((lane >> 3) & 3);   // V stage: source chunk for this lane

    // per-lane LDS base pointers (element = short)
    const short* k0p = &Ks[0][lm][g*8];        // QK read: kc + 32*(ss^lm); second subtile +8192
    const short* k1p = &Ks[1][lm][g*8];
    const int vcid = g ^ ((lm >> 1) & 3);
    const short* v0p = &Vs[0][lm][vcid*8];     // PV read: vc + dt*512 (literal), dt 0..31
    const short* v1p = &Vs[1][lm][vcid*8];

    // stage k-tile T (global index) into buffer BUF; 8 waves split the 64 DMA instrs
    #define STAGE_KV(T, BUF) do {                                                  \
        const short* kt_ = kp + (size_t)(T) * KT * D;                              \
        const int ksv_ = (T) * KT;                                                 \
        _Pragma("unroll")                                                          \
        for (int i_ = 0; i_ < 4; ++i_) {                                           \
            int r_ = 4*w + i_;                                                     \
            int c_ = (lane ^ ((r_ & 15) << 2)) & 63;                               \
            __builtin_amdgcn_global_load_lds(                                      \
                (const __attribute__((address_space(1))) void*)(kt_ + (size_t)r_*D + c_*8), \
                (__attribute__((address_space(3))) void*)(&Ks[BUF][r_][0]),        \
                16, 0, 0);                                                         \
        }                                                                          \
        _Pragma("unroll")                                                          \
        for (int i_ = 0; i_ < 4; ++i_) {                                           \
            int d0_ = 64*w + 16*i_;                                                \
            int row_ = d0_ + (lane >> 2);                                          \
            __builtin_amdgcn_global_load_lds(                                      \
                (const __attribute__((address_space(1))) void*)(vp + (size_t)row_*TT + ksv_ + vswz*8), \
                (__attribute__((address_space(3))) void*)(&Vs[BUF][d0_][0]),       \
                16, 0, 0);                                                         \
        }                                                                          \
    } while (0)

    #pragma unroll 1
    for (int phase = 0; phase < 2; ++phase) {
        const int qb = phase ? (31 - pr) : pr;
        const int qbase = qb * 128;
        const int qrow  = qbase + 16*qgp + lm;
        const int t0  = s * (qb + 1);          // this quarter's start k-tile
        const int cnt = qb + 1;                // k-tiles in this quarter

        // hoist Q fragments for this phase: lane (g,lm) holds Q[qrow][32ss+8g .. +8]
        short8v qf[16];
        #pragma unroll
        for (int ss = 0; ss < 16; ++ss)
            qf[ss] = *reinterpret_cast<const short8v*>(qp + (size_t)qrow*D + 32*ss + 8*g);

        float4v acc[32];                       // O^T: col=q=lm, rows=dims 16*dt+4g+r
        #pragma unroll
        for (int i = 0; i < 32; ++i) acc[i] = (float4v){0.f,0.f,0.f,0.f};
        float m_r = -INFINITY, l_par = 0.f;    // l_par: this lane's 8-kj partial sum

        __syncthreads();                       // prev phase's LDS reads done before re-staging
        STAGE_KV(t0, 0);

        for (int i = 0; i < cnt; ++i) {
            const int t = t0 + i;
            const int ks0 = t * KT;
            __syncthreads();                   // own vmcnt drained pre-barrier -> stage(i)
                                               // landed for all waves; reads of i-1 done
            if (i + 1 < cnt) STAGE_KV(t + 1, (i + 1) & 1);

            const short* kc = (i & 1) ? k1p : k0p;
            const short* vc = (i & 1) ? v1p : v0p;

            // S^T[kj][q]: 4 independent 8-deep MFMA chains (priority-boosted)
            float4v s0a = (float4v){0.f,0.f,0.f,0.f}, s0b = (float4v){0.f,0.f,0.f,0.f};
            float4v s1a = (float4v){0.f,0.f,0.f,0.f}, s1b = (float4v){0.f,0.f,0.f,0.f};
            __builtin_amdgcn_s_setprio(1);
            #pragma unroll
            for (int ss = 0; ss < 16; ++ss) {
                int off = (ss ^ lm) << 5;      // shorts: 32*(ss^lm)
                short8v a0 = *reinterpret_cast<const short8v*>(kc + off);
                short8v a1 = *reinterpret_cast<const short8v*>(kc + off + 8192);
                if (ss & 1) {
                    s0b = __builtin_amdgcn_mfma_f32_16x16x32_bf16(a0, qf[ss], s0b, 0, 0, 0);
                    s1b = __builtin_amdgcn_mfma_f32_16x16x32_bf16(a1, qf[ss], s1b, 0, 0, 0);
                } else {
                    s0a = __builtin_amdgcn_mfma_f32_16x16x32_bf16(a0, qf[ss], s0a, 0, 0, 0);
                    s1a = __builtin_amdgcn_mfma_f32_16x16x32_bf16(a1, qf[ss], s1a, 0, 0, 0);
                }
            }
            __builtin_amdgcn_s_setprio(0);
            float4v s0, s1;
            #pragma unroll
            for (int r = 0; r < 4; ++r) { s0[r] = s0a[r] + s0b[r]; s1[r] = s1a[r] + s1b[r]; }

            // causal mask; lane holds kj = ks0 + sigma(g,e) for q = qrow
            float p[8];
            #pragma unroll
            for (int r = 0; r < 4; ++r) {
                int kj0 = ks0 + 4*g + r;
                p[r]     = (kj0      <= qrow) ? s0[r] : -3.0e38f;
                p[r + 4] = (kj0 + 16 <= qrow) ? s1[r] : -3.0e38f;
            }
            float mx = p[0];
            #pragma unroll
            for (int i2 = 1; i2 < 8; ++i2) mx = fmaxf(mx, p[i2]);

            // defer-max: row-max shuffles + rescale only when slack exceeded (or first tile)
            if (!__all(mx <= m_r + 8.f)) {
                float mrow = fmaxf(mx, __shfl_xor(mx, 16));
                mrow = fmaxf(mrow, __shfl_xor(mrow, 32));
                mrow = fmaxf(mrow, m_r);
                float corr = __expf(m_r - mrow);   // first tile: expf(-inf)=0
                m_r = mrow;
                l_par *= corr;
                #pragma unroll
                for (int dt = 0; dt < 32; ++dt) {
                    acc[dt][0] *= corr; acc[dt][1] *= corr;
                    acc[dt][2] *= corr; acc[dt][3] *= corr;
                }
            }
            // gated exp: fully-masked entries (incl. all-masked rows where m_r==-3e38) -> 0
            #pragma unroll
            for (int i2 = 0; i2 < 8; ++i2) {
                float e = __expf(p[i2] - m_r);
                p[i2] = (p[i2] > -1.0e37f) ? e : 0.f;
                l_par += p[i2];
            }

            // P fragment (lane-local): B-operand elems = P[q=lm][sigma(g,e)], values <= e^8
            short8v pf;
            #pragma unroll
            for (int i2 = 0; i2 < 8; ++i2) pf[i2] = f2bf(p[i2]);

            // PV (O^T): A = V^T rows (full 512 dims), literal offsets, B = pf
            __builtin_amdgcn_s_setprio(1);
            #pragma unroll
            for (int dt = 0; dt < 32; ++dt) {
                short8v vf = *reinterpret_cast<const short8v*>(vc + dt*512);
                acc[dt] = __builtin_amdgcn_mfma_f32_16x16x32_bf16(vf, pf, acc[dt], 0, 0, 0);
            }
            __builtin_amdgcn_s_setprio(0);
        }

        // phase epilogue: reduce l across the row's 4 g-lanes; store UNNORMALIZED U + (m,l)
        float l = l_par + __shfl_xor(l_par, 16);
        l += __shfl_xor(l, 32);
        const int orow = qbase + 16*qgp + lm;
        short* up = Uo + (size_t)(b*TT + orow)*D;
        #pragma unroll
        for (int dt = 0; dt < 32; ++dt) {
            short4v o = { f2bf(acc[dt][0]), f2bf(acc[dt][1]),
                          f2bf(acc[dt][2]), f2bf(acc[dt][3]) };
            *reinterpret_cast<short4v*>(up + 16*dt + 4*g) = o;
        }
        if (g == 0) {                          // one writer per row (lanes 0..15)
            mo[(size_t)b*TT + orow] = m_r;
            lo[(size_t)b*TT + orow] = l;
        }
    }
    #undef STAGE_KV
}

// ============ Merge the four key-quarters: O = sum_s U_s*w_s / sum_s l_s*w_s ============
__global__ __launch_bounds__(256) void merge_quads(
    const __hip_bfloat16* __restrict__ U0, const __hip_bfloat16* __restrict__ U1,
    const __hip_bfloat16* __restrict__ U2, const __hip_bfloat16* __restrict__ U3,
    const float* __restrict__ mArr, const float* __restrict__ lArr,
    __hip_bfloat16* __restrict__ ctx)
{
    const int BT = BB * TT;
    const int gidx = blockIdx.x * 256 + threadIdx.x;   // one thread per 8 cols
    const int row = gidx >> 6;
    const int c = (gidx & 63) * 8;
    float m0 = mArr[row], m1 = mArr[BT + row], m2 = mArr[2*BT + row], m3 = mArr[3*BT + row];
    float ms = fmaxf(fmaxf(m0, m1), fmaxf(m2, m3));
    float w0 = __expf(m0 - ms), w1 = __expf(m1 - ms);
    float w2 = __expf(m2 - ms), w3 = __expf(m3 - ms);
    float l = lArr[row]*w0 + lArr[BT + row]*w1 + lArr[2*BT + row]*w2 + lArr[3*BT + row]*w3;
    float inv = 1.f / l;
    w0 *= inv; w1 *= inv; w2 *= inv; w3 *= inv;
    size_t off = (size_t)row * D + c;
    short8v a = *reinterpret_cast<const short8v*>((const short*)U0 + off);
    short8v b = *reinterpret_cast<const short8v*>((const short*)U1 + off);
    short8v d = *reinterpret_cast<const short8v*>((const short*)U2 + off);
    short8v e = *reinterpret_cast<const short8v*>((const short*)U3 + off);
    short8v o;
    #pragma unroll
    for (int i = 0; i < 8; ++i)
        o[i] = f2bf(bf2f(a[i])*w0 + bf2f(b[i])*w1 + bf2f(d[i])*w2 + bf2f(e[i])*w3);
    *reinterpret_cast<short8v*>((short*)ctx + off) = o;
}

// ============ Output projection: d_out[t][e] = sum_d ctx[t][d] * Wo[e][d], f32 out ============
__global__ __launch_bounds__(256) void gemm_out(
    const __hip_bfloat16* __restrict__ Ab, const float* __restrict__ W,
    float* __restrict__ Cf)
{
    __shared__ short As[64][72];
    __shared__ short Bs[64][72];
    const int tid = threadIdx.x;
    const int m0 = blockIdx.x * 64, n0 = blockIdx.y * 64;
    const int w = tid >> 6, lane = tid & 63, lm = lane & 15, g = lane >> 4;
    const short* Ap = (const short*)Ab;

    float4v acc[4];
    #pragma unroll
    for (int i = 0; i < 4; ++i) acc[i] = (float4v){0.f,0.f,0.f,0.f};

    for (int k0 = 0; k0 < 512; k0 += 64) {
        __syncthreads();
        #pragma unroll
        for (int u = 0; u < 2; ++u) {          // stage A (bf16 ctx)
            int ch = tid + 256*u;
            int r = ch >> 3, c = (ch & 7) * 8;
            *reinterpret_cast<short8v*>(&As[r][c]) =
                *reinterpret_cast<const short8v*>(Ap + (size_t)(m0 + r)*512 + k0 + c);
        }
        #pragma unroll
        for (int u = 0; u < 4; ++u) {          // stage B (Wo f32 -> bf16)
            int ch = tid + 256*u;
            int r = ch >> 4, c = (ch & 15) * 4;
            float4 wv = *reinterpret_cast<const float4*>(W + (size_t)(n0 + r)*512 + k0 + c);
            short4v sv = { f2bf(wv.x), f2bf(wv.y), f2bf(wv.z), f2bf(wv.w) };
            *reinterpret_cast<short4v*>(&Bs[r][c]) = sv;
        }
        __syncthreads();
        #pragma unroll
        for (int ks = 0; ks < 2; ++ks) {
            short8v a = *reinterpret_cast<const short8v*>(&As[16*w + lm][ks*32 + 8*g]);
            #pragma unroll
            for (int nt = 0; nt < 4; ++nt) {
                short8v bv = *reinterpret_cast<const short8v*>(&Bs[16*nt + lm][ks*32 + 8*g]);
                acc[nt] = __builtin_amdgcn_mfma_f32_16x16x32_bf16(a, bv, acc[nt], 0, 0, 0);
            }
        }
    }
    #pragma unroll
    for (int nt = 0; nt < 4; ++nt)
        #pragma unroll
        for (int r = 0; r < 4; ++r) {
            int row = m0 + 16*w + 4*g + r;
            int col = n0 + 16*nt + lm;
            Cf[(size_t)row*512 + col] = acc[nt][r];
        }
}

extern "C" void kernel_launch(void* const* d_in, const int* in_sizes, int n_in,
                              void* d_out, int out_size, void* d_ws, size_t ws_size,
                              hipStream_t stream) {
    const float* x  = (const float*)d_in[0];
    const float* Wq = (const float*)d_in[1];
    const float* Wk = (const float*)d_in[2];
    const float* Wv = (const float*)d_in[3];
    const float* Wo = (const float*)d_in[4];
    float* out = (float*)d_out;

    const size_t n = (size_t)BB * TT * D;                 // 8.4M elems
    __hip_bfloat16* qb_  = (__hip_bfloat16*)d_ws;
    __hip_bfloat16* kb_  = qb_ + n;
    __hip_bfloat16* vb_  = kb_ + n;
    __hip_bfloat16* vt_  = vb_ + n;
    __hip_bfloat16* ctxb = vt_ + n;                       // [0, 5n) bf16 = 84MB
    __hip_bfloat16* U1   = ctxb + n;                      // 3 x 16.8MB bf16
    __hip_bfloat16* U2   = U1 + n;
    __hip_bfloat16* U3   = U2 + n;
    float* mArr = (float*)(U3 + n);                       // 4 x BT f32 = 1MB
    float* lArr = mArr + (size_t)4 * BB * TT;             // 4 x BT f32 = 1MB
    __hip_bfloat16* U0 = (__hip_bfloat16*)out;            // d_out as scratch (overwritten later)

    gemm_qkv<<<dim3(256, 8), 256, 0, stream>>>(x, Wq, Wk, Wv, qb_, kb_, vb_);
    transpose_v<<<dim3(TT / 32, BB), 256, 0, stream>>>(vb_, vt_);
    attn_split<<<dim3(64 * BB), 512, 0, stream>>>(qb_, kb_, vt_, U0, U1, U2, U3, mArr, lArr);
    merge_quads<<<dim3(BB * TT / 4), 256, 0, stream>>>(U0, U1, U2, U3, mArr, lArr, ctxb);
    gemm_out<<<dim3(256, 8, 1), 256, 0, stream>>>(ctxb, Wo, out);
}

// Round 17
// 239.615 us; speedup vs baseline: 1.8517x; 1.0190x over previous
//
#include <hip/hip_runtime.h>
#include <hip/hip_bf16.h>
#include <math.h>

#define D 512
#define BB 4
#define TT 4096
#define KT 32

typedef __attribute__((ext_vector_type(8))) short short8v;
typedef __attribute__((ext_vector_type(4))) short short4v;
typedef __attribute__((ext_vector_type(4))) float float4v;

__device__ inline short f2bf(float x) {
    __hip_bfloat16 h = __float2bfloat16(x);
    return *reinterpret_cast<short*>(&h);
}
__device__ inline float bf2f(short s) {
    __hip_bfloat16 h = *reinterpret_cast<__hip_bfloat16*>(&s);
    return __bfloat162float(h);
}

// ============ Fused QKV projection + V-transpose ============
// C_z[t][e] = alpha_z * sum_d x[t][d] * W_z[e][d], bf16 out. x staged+converted ONCE.
// q,k written row-major; v written DIRECTLY into the sigma-permuted transposed layout
// vt[b][d][t-permuted] via an LDS round-trip (transposed bf16 store, inverse-perm read,
// contiguous 32B global writes along t) -- eliminates the standalone transpose kernel.
__global__ __launch_bounds__(256) void gemm_qkv(
    const float* __restrict__ x,
    const float* __restrict__ Wq, const float* __restrict__ Wk, const float* __restrict__ Wv,
    __hip_bfloat16* __restrict__ q, __hip_bfloat16* __restrict__ k, __hip_bfloat16* __restrict__ vt)
{
    __shared__ short As[64][72];       // +8 bf16 pad -> conflict-floor b128 reads
    __shared__ short Bs[3][64][72];
    __shared__ short Ts[64][66];       // V-tile transpose buffer [d_local][t_local]
    const int tid = threadIdx.x;
    const int m0 = blockIdx.x * 64, n0 = blockIdx.y * 64;
    const int w = tid >> 6, lane = tid & 63, lm = lane & 15, g = lane >> 4;

    float4v acc[3][4];
    #pragma unroll
    for (int z = 0; z < 3; ++z)
        #pragma unroll
        for (int i = 0; i < 4; ++i) acc[z][i] = (float4v){0.f,0.f,0.f,0.f};

    for (int k0 = 0; k0 < 512; k0 += 64) {
        __syncthreads();
        #pragma unroll
        for (int u = 0; u < 4; ++u) {          // stage A (x), convert f32->bf16, ONCE
            int ch = tid + 256*u;
            int r = ch >> 4, c = (ch & 15) * 4;
            float4 xv = *reinterpret_cast<const float4*>(x + (size_t)(m0 + r)*512 + k0 + c);
            short4v sv = { f2bf(xv.x), f2bf(xv.y), f2bf(xv.z), f2bf(xv.w) };
            *reinterpret_cast<short4v*>(&As[r][c]) = sv;
        }
        #pragma unroll
        for (int z = 0; z < 3; ++z) {          // stage B for all 3 weight matrices
            const float* W = (z == 0) ? Wq : (z == 1) ? Wk : Wv;
            #pragma unroll
            for (int u = 0; u < 4; ++u) {
                int ch = tid + 256*u;
                int r = ch >> 4, c = (ch & 15) * 4;
                float4 wv = *reinterpret_cast<const float4*>(W + (size_t)(n0 + r)*512 + k0 + c);
                short4v sv = { f2bf(wv.x), f2bf(wv.y), f2bf(wv.z), f2bf(wv.w) };
                *reinterpret_cast<short4v*>(&Bs[z][r][c]) = sv;
            }
        }
        __syncthreads();
        #pragma unroll
        for (int ks = 0; ks < 2; ++ks) {
            short8v a = *reinterpret_cast<const short8v*>(&As[16*w + lm][ks*32 + 8*g]);
            #pragma unroll
            for (int z = 0; z < 3; ++z)
                #pragma unroll
                for (int nt = 0; nt < 4; ++nt) {
                    short8v bv = *reinterpret_cast<const short8v*>(&Bs[z][16*nt + lm][ks*32 + 8*g]);
                    acc[z][nt] = __builtin_amdgcn_mfma_f32_16x16x32_bf16(a, bv, acc[z][nt], 0, 0, 0);
                }
        }
    }

    // q, k: direct row-major writes (D layout: row = 4*(lane>>4)+reg, col = lane&15)
    #pragma unroll
    for (int z = 0; z < 2; ++z) {
        __hip_bfloat16* C = (z == 0) ? q : k;
        const float alpha = (z == 0) ? 0.044194173824159216f : 1.f;   // fold 1/sqrt(512) into q
        #pragma unroll
        for (int nt = 0; nt < 4; ++nt)
            #pragma unroll
            for (int r = 0; r < 4; ++r) {
                int row = m0 + 16*w + 4*g + r;
                int col = n0 + 16*nt + lm;
                C[(size_t)row*512 + col] = __float2bfloat16(acc[z][nt][r] * alpha);
            }
    }

    // v: transposed store into Ts[d_local][t_local] (bf16), then sigma-permuted coalesced write
    #pragma unroll
    for (int nt = 0; nt < 4; ++nt)
        #pragma unroll
        for (int r = 0; r < 4; ++r)
            Ts[16*nt + lm][16*w + 4*g + r] = f2bf(acc[2][nt][r]);
    __syncthreads();

    {
        const int dloc = tid >> 2;             // 0..63
        const int qs   = tid & 3;              // 16-t chunk
        const int bb   = m0 >> 12;             // batch (TT=4096; 64-row tiles never straddle)
        const int tb   = m0 & (TT - 1);
        short tmp[16];
        #pragma unroll
        for (int i = 0; i < 16; ++i) {
            int tp = qs*16 + i;
            int blk = tp & 32;
            int p = tp & 31;
            int tloc = blk + 16*((p & 7) >> 2) + 4*(p >> 3) + (p & 3);   // inverse sigma perm
            tmp[i] = Ts[dloc][tloc];
        }
        short* dst = (short*)vt + (size_t)bb*D*TT + (size_t)(n0 + dloc)*TT + tb + qs*16;
        *reinterpret_cast<short8v*>(dst)     = *reinterpret_cast<short8v*>(&tmp[0]);
        *reinterpret_cast<short8v*>(dst + 8) = *reinterpret_cast<short8v*>(&tmp[8]);
    }
}

// ============ Flash attention, QB=128, 4-way split-K + triangle pairing ============
// R15-verbatim structure (8 full-d waves, dbuf K+V DMA, source-XOR swizzles, pointer-
// toggle, O^T PV, defer-max, per-lane l, gated exp) + s_setprio(1) around MFMA clusters.
__global__ __launch_bounds__(512, 1) void attn_split(
    const __hip_bfloat16* __restrict__ qg, const __hip_bfloat16* __restrict__ kg,
    const __hip_bfloat16* __restrict__ vtg,
    __hip_bfloat16* __restrict__ U0, __hip_bfloat16* __restrict__ U1,
    __hip_bfloat16* __restrict__ U2, __hip_bfloat16* __restrict__ U3,
    float* __restrict__ mArr, float* __restrict__ lArr)
{
    __shared__ short Ks[2][KT][512];           // 64KB; row r chunk c holds K chunk c^(4*(r&15))
    __shared__ short Vs[2][512][32];           // 64KB; row d chunk c holds vt chunk c^((d>>1)&3)

    const int tid = threadIdx.x;
    const int w = tid >> 6, lane = tid & 63, lm = lane & 15, g = lane >> 4;
    const int qgp = w;                         // q-group 0..7 (full-d wave)
    const int idx = blockIdx.x;
    const int b  = idx & 3;                    // batch -> XCD spread
    const int u  = idx >> 2;
    const int pr = u >> 2;                     // pair index 0..15
    const int s  = u & 3;                      // key-quarter

    const short* qp = (const short*)qg  + (size_t)b*TT*D;
    const short* kp = (const short*)kg  + (size_t)b*TT*D;
    const short* vp = (const short*)vtg + (size_t)b*D*TT;

    short* Uo = (short*)((s == 0) ? U0 : (s == 1) ? U1 : (s == 2) ? U2 : U3);
    float* mo = mArr + (size_t)s * BB * TT;
    float* lo = lArr + (size_t)s * BB * TT;

    const int vswz = (lane & 3) ^ ((lane >> 3) & 3);   // V stage: source chunk for this lane

    // per-lane LDS base pointers (element = short)
    const short* k0p = &Ks[0][lm][g*8];        // QK read: kc + 32*(ss^lm); second subtile +8192
    const short* k1p = &Ks[1][lm][g*8];
    const int vcid = g ^ ((lm >> 1) & 3);
    const short* v0p = &Vs[0][lm][vcid*8];     // PV read: vc + dt*512 (literal), dt 0..31
    const short* v1p = &Vs[1][lm][vcid*8];

    // stage k-tile T (global index) into buffer BUF; 8 waves split the 64 DMA instrs
    #define STAGE_KV(T, BUF) do {                                                  \
        const short* kt_ = kp + (size_t)(T) * KT * D;                              \
        const int ksv_ = (T) * KT;                                                 \
        _Pragma("unroll")                                                          \
        for (int i_ = 0; i_ < 4; ++i_) {                                           \
            int r_ = 4*w + i_;                                                     \
            int c_ = (lane ^ ((r_ & 15) << 2)) & 63;                               \
            __builtin_amdgcn_global_load_lds(                                      \
                (const __attribute__((address_space(1))) void*)(kt_ + (size_t)r_*D + c_*8), \
                (__attribute__((address_space(3))) void*)(&Ks[BUF][r_][0]),        \
                16, 0, 0);                                                         \
        }                                                                          \
        _Pragma("unroll")                                                          \
        for (int i_ = 0; i_ < 4; ++i_) {                                           \
            int d0_ = 64*w + 16*i_;                                                \
            int row_ = d0_ + (lane >> 2);                                          \
            __builtin_amdgcn_global_load_lds(                                      \
                (const __attribute__((address_space(1))) void*)(vp + (size_t)row_*TT + ksv_ + vswz*8), \
                (__attribute__((address_space(3))) void*)(&Vs[BUF][d0_][0]),       \
                16, 0, 0);                                                         \
        }                                                                          \
    } while (0)

    #pragma unroll 1
    for (int phase = 0; phase < 2; ++phase) {
        const int qb = phase ? (31 - pr) : pr;
        const int qbase = qb * 128;
        const int qrow  = qbase + 16*qgp + lm;
        const int t0  = s * (qb + 1);          // this quarter's start k-tile
        const int cnt = qb + 1;                // k-tiles in this quarter

        // hoist Q fragments for this phase: lane (g,lm) holds Q[qrow][32ss+8g .. +8]
        short8v qf[16];
        #pragma unroll
        for (int ss = 0; ss < 16; ++ss)
            qf[ss] = *reinterpret_cast<const short8v*>(qp + (size_t)qrow*D + 32*ss + 8*g);

        float4v acc[32];                       // O^T: col=q=lm, rows=dims 16*dt+4g+r
        #pragma unroll
        for (int i = 0; i < 32; ++i) acc[i] = (float4v){0.f,0.f,0.f,0.f};
        float m_r = -INFINITY, l_par = 0.f;    // l_par: this lane's 8-kj partial sum

        __syncthreads();                       // prev phase's LDS reads done before re-staging
        STAGE_KV(t0, 0);

        for (int i = 0; i < cnt; ++i) {
            const int t = t0 + i;
            const int ks0 = t * KT;
            __syncthreads();                   // own vmcnt drained pre-barrier -> stage(i)
                                               // landed for all waves; reads of i-1 done
            if (i + 1 < cnt) STAGE_KV(t + 1, (i + 1) & 1);

            const short* kc = (i & 1) ? k1p : k0p;
            const short* vc = (i & 1) ? v1p : v0p;

            // S^T[kj][q]: 4 independent 8-deep MFMA chains (priority-boosted)
            float4v s0a = (float4v){0.f,0.f,0.f,0.f}, s0b = (float4v){0.f,0.f,0.f,0.f};
            float4v s1a = (float4v){0.f,0.f,0.f,0.f}, s1b = (float4v){0.f,0.f,0.f,0.f};
            __builtin_amdgcn_s_setprio(1);
            #pragma unroll
            for (int ss = 0; ss < 16; ++ss) {
                int off = (ss ^ lm) << 5;      // shorts: 32*(ss^lm)
                short8v a0 = *reinterpret_cast<const short8v*>(kc + off);
                short8v a1 = *reinterpret_cast<const short8v*>(kc + off + 8192);
                if (ss & 1) {
                    s0b = __builtin_amdgcn_mfma_f32_16x16x32_bf16(a0, qf[ss], s0b, 0, 0, 0);
                    s1b = __builtin_amdgcn_mfma_f32_16x16x32_bf16(a1, qf[ss], s1b, 0, 0, 0);
                } else {
                    s0a = __builtin_amdgcn_mfma_f32_16x16x32_bf16(a0, qf[ss], s0a, 0, 0, 0);
                    s1a = __builtin_amdgcn_mfma_f32_16x16x32_bf16(a1, qf[ss], s1a, 0, 0, 0);
                }
            }
            __builtin_amdgcn_s_setprio(0);
            float4v s0, s1;
            #pragma unroll
            for (int r = 0; r < 4; ++r) { s0[r] = s0a[r] + s0b[r]; s1[r] = s1a[r] + s1b[r]; }

            // causal mask; lane holds kj = ks0 + sigma(g,e) for q = qrow
            float p[8];
            #pragma unroll
            for (int r = 0; r < 4; ++r) {
                int kj0 = ks0 + 4*g + r;
                p[r]     = (kj0      <= qrow) ? s0[r] : -3.0e38f;
                p[r + 4] = (kj0 + 16 <= qrow) ? s1[r] : -3.0e38f;
            }
            float mx = p[0];
            #pragma unroll
            for (int i2 = 1; i2 < 8; ++i2) mx = fmaxf(mx, p[i2]);

            // defer-max: row-max shuffles + rescale only when slack exceeded (or first tile)
            if (!__all(mx <= m_r + 8.f)) {
                float mrow = fmaxf(mx, __shfl_xor(mx, 16));
                mrow = fmaxf(mrow, __shfl_xor(mrow, 32));
                mrow = fmaxf(mrow, m_r);
                float corr = __expf(m_r - mrow);   // first tile: expf(-inf)=0
                m_r = mrow;
                l_par *= corr;
                #pragma unroll
                for (int dt = 0; dt < 32; ++dt) {
                    acc[dt][0] *= corr; acc[dt][1] *= corr;
                    acc[dt][2] *= corr; acc[dt][3] *= corr;
                }
            }
            // gated exp: fully-masked entries (incl. all-masked rows where m_r==-3e38) -> 0
            #pragma unroll
            for (int i2 = 0; i2 < 8; ++i2) {
                float e = __expf(p[i2] - m_r);
                p[i2] = (p[i2] > -1.0e37f) ? e : 0.f;
                l_par += p[i2];
            }

            // P fragment (lane-local): B-operand elems = P[q=lm][sigma(g,e)], values <= e^8
            short8v pf;
            #pragma unroll
            for (int i2 = 0; i2 < 8; ++i2) pf[i2] = f2bf(p[i2]);

            // PV (O^T): A = V^T rows (full 512 dims), literal offsets, B = pf
            __builtin_amdgcn_s_setprio(1);
            #pragma unroll
            for (int dt = 0; dt < 32; ++dt) {
                short8v vf = *reinterpret_cast<const short8v*>(vc + dt*512);
                acc[dt] = __builtin_amdgcn_mfma_f32_16x16x32_bf16(vf, pf, acc[dt], 0, 0, 0);
            }
            __builtin_amdgcn_s_setprio(0);
        }

        // phase epilogue: reduce l across the row's 4 g-lanes; store UNNORMALIZED U + (m,l)
        float l = l_par + __shfl_xor(l_par, 16);
        l += __shfl_xor(l, 32);
        const int orow = qbase + 16*qgp + lm;
        short* up = Uo + (size_t)(b*TT + orow)*D;
        #pragma unroll
        for (int dt = 0; dt < 32; ++dt) {
            short4v o = { f2bf(acc[dt][0]), f2bf(acc[dt][1]),
                          f2bf(acc[dt][2]), f2bf(acc[dt][3]) };
            *reinterpret_cast<short4v*>(up + 16*dt + 4*g) = o;
        }
        if (g == 0) {                          // one writer per row (lanes 0..15)
            mo[(size_t)b*TT + orow] = m_r;
            lo[(size_t)b*TT + orow] = l;
        }
    }
    #undef STAGE_KV
}

// ============ Merge the four key-quarters: O = sum_s U_s*w_s / sum_s l_s*w_s ============
__global__ __launch_bounds__(256) void merge_quads(
    const __hip_bfloat16* __restrict__ U0, const __hip_bfloat16* __restrict__ U1,
    const __hip_bfloat16* __restrict__ U2, const __hip_bfloat16* __restrict__ U3,
    const float* __restrict__ mArr, const float* __restrict__ lArr,
    __hip_bfloat16* __restrict__ ctx)
{
    const int BT = BB * TT;
    const int gidx = blockIdx.x * 256 + threadIdx.x;   // one thread per 8 cols
    const int row = gidx >> 6;
    const int c = (gidx & 63) * 8;
    float m0 = mArr[row], m1 = mArr[BT + row], m2 = mArr[2*BT + row], m3 = mArr[3*BT + row];
    float ms = fmaxf(fmaxf(m0, m1), fmaxf(m2, m3));
    float w0 = __expf(m0 - ms), w1 = __expf(m1 - ms);
    float w2 = __expf(m2 - ms), w3 = __expf(m3 - ms);
    float l = lArr[row]*w0 + lArr[BT + row]*w1 + lArr[2*BT + row]*w2 + lArr[3*BT + row]*w3;
    float inv = 1.f / l;
    w0 *= inv; w1 *= inv; w2 *= inv; w3 *= inv;
    size_t off = (size_t)row * D + c;
    short8v a = *reinterpret_cast<const short8v*>((const short*)U0 + off);
    short8v b = *reinterpret_cast<const short8v*>((const short*)U1 + off);
    short8v d = *reinterpret_cast<const short8v*>((const short*)U2 + off);
    short8v e = *reinterpret_cast<const short8v*>((const short*)U3 + off);
    short8v o;
    #pragma unroll
    for (int i = 0; i < 8; ++i)
        o[i] = f2bf(bf2f(a[i])*w0 + bf2f(b[i])*w1 + bf2f(d[i])*w2 + bf2f(e[i])*w3);
    *reinterpret_cast<short8v*>((short*)ctx + off) = o;
}

// ============ Output projection: d_out[t][e] = sum_d ctx[t][d] * Wo[e][d], f32 out ============
__global__ __launch_bounds__(256) void gemm_out(
    const __hip_bfloat16* __restrict__ Ab, const float* __restrict__ W,
    float* __restrict__ Cf)
{
    __shared__ short As[64][72];
    __shared__ short Bs[64][72];
    const int tid = threadIdx.x;
    const int m0 = blockIdx.x * 64, n0 = blockIdx.y * 64;
    const int w = tid >> 6, lane = tid & 63, lm = lane & 15, g = lane >> 4;
    const short* Ap = (const short*)Ab;

    float4v acc[4];
    #pragma unroll
    for (int i = 0; i < 4; ++i) acc[i] = (float4v){0.f,0.f,0.f,0.f};

    for (int k0 = 0; k0 < 512; k0 += 64) {
        __syncthreads();
        #pragma unroll
        for (int u = 0; u < 2; ++u) {          // stage A (bf16 ctx)
            int ch = tid + 256*u;
            int r = ch >> 3, c = (ch & 7) * 8;
            *reinterpret_cast<short8v*>(&As[r][c]) =
                *reinterpret_cast<const short8v*>(Ap + (size_t)(m0 + r)*512 + k0 + c);
        }
        #pragma unroll
        for (int u = 0; u < 4; ++u) {          // stage B (Wo f32 -> bf16)
            int ch = tid + 256*u;
            int r = ch >> 4, c = (ch & 15) * 4;
            float4 wv = *reinterpret_cast<const float4*>(W + (size_t)(n0 + r)*512 + k0 + c);
            short4v sv = { f2bf(wv.x), f2bf(wv.y), f2bf(wv.z), f2bf(wv.w) };
            *reinterpret_cast<short4v*>(&Bs[r][c]) = sv;
        }
        __syncthreads();
        #pragma unroll
        for (int ks = 0; ks < 2; ++ks) {
            short8v a = *reinterpret_cast<const short8v*>(&As[16*w + lm][ks*32 + 8*g]);
            #pragma unroll
            for (int nt = 0; nt < 4; ++nt) {
                short8v bv = *reinterpret_cast<const short8v*>(&Bs[16*nt + lm][ks*32 + 8*g]);
                acc[nt] = __builtin_amdgcn_mfma_f32_16x16x32_bf16(a, bv, acc[nt], 0, 0, 0);
            }
        }
    }
    #pragma unroll
    for (int nt = 0; nt < 4; ++nt)
        #pragma unroll
        for (int r = 0; r < 4; ++r) {
            int row = m0 + 16*w + 4*g + r;
            int col = n0 + 16*nt + lm;
            Cf[(size_t)row*512 + col] = acc[nt][r];
        }
}

extern "C" void kernel_launch(void* const* d_in, const int* in_sizes, int n_in,
                              void* d_out, int out_size, void* d_ws, size_t ws_size,
                              hipStream_t stream) {
    const float* x  = (const float*)d_in[0];
    const float* Wq = (const float*)d_in[1];
    const float* Wk = (const float*)d_in[2];
    const float* Wv = (const float*)d_in[3];
    const float* Wo = (const float*)d_in[4];
    float* out = (float*)d_out;

    const size_t n = (size_t)BB * TT * D;                 // 8.4M elems
    __hip_bfloat16* qb_  = (__hip_bfloat16*)d_ws;
    __hip_bfloat16* kb_  = qb_ + n;
    __hip_bfloat16* vt_  = kb_ + n;                       // sigma-permuted V^T (written by gemm_qkv)
    __hip_bfloat16* ctxb = vt_ + n;
    __hip_bfloat16* U1   = ctxb + n;                      // 3 x 16.8MB bf16
    __hip_bfloat16* U2   = U1 + n;
    __hip_bfloat16* U3   = U2 + n;
    float* mArr = (float*)(U3 + n);                       // 4 x BT f32 = 1MB
    float* lArr = mArr + (size_t)4 * BB * TT;             // 4 x BT f32 = 1MB
    __hip_bfloat16* U0 = (__hip_bfloat16*)out;            // d_out as scratch (overwritten later)

    gemm_qkv<<<dim3(256, 8), 256, 0, stream>>>(x, Wq, Wk, Wv, qb_, kb_, vt_);
    attn_split<<<dim3(64 * BB), 512, 0, stream>>>(qb_, kb_, vt_, U0, U1, U2, U3, mArr, lArr);
    merge_quads<<<dim3(BB * TT / 4), 256, 0, stream>>>(U0, U1, U2, U3, mArr, lArr, ctxb);
    gemm_out<<<dim3(256, 8, 1), 256, 0, stream>>>(ctxb, Wo, out);
}